// Round 7
// baseline (970.645 us; speedup 1.0000x reference)
//
#include <hip/hip_runtime.h>
#include <stdint.h>

#define B_ 8
#define C_ 256
#define N_ 4096
#define K_ 64
#define NH_ 8
#define FF_ 1024
#define L_ 3
#define M_ (B_*N_)
#define SCALE_ 0.17677669529663687f

typedef float f32x4 __attribute__((ext_vector_type(4)));
typedef __bf16 v8bf __attribute__((ext_vector_type(8)));

__device__ __forceinline__ float b2f(unsigned short h){
  union { uint32_t u; float f; } v; v.u = ((uint32_t)h) << 16; return v.f;
}
__device__ __forceinline__ unsigned short f2b(float f){
  union { float f; uint32_t u; } v; v.f = f;
  uint32_t r = v.u + 0x7fffu + ((v.u >> 16) & 1u);
  return (unsigned short)(r >> 16);
}
__device__ __forceinline__ void gload_lds16(const void* g, void* l){
  __builtin_amdgcn_global_load_lds(
      (const __attribute__((address_space(1))) unsigned int*)g,
      (__attribute__((address_space(3))) unsigned int*)l, 16, 0, 0);
}

// ---------------- fp32 -> bf16 convert ----------------
__global__ __launch_bounds__(256) void k_f32_to_bf16(const float* __restrict__ src,
                                                     unsigned short* __restrict__ dst, int n){
  int i4 = (blockIdx.x*256 + threadIdx.x)*4;
  if (i4 >= n) return;
  float4 v = *(const float4*)(src + i4);
  uint32_t p0 = (uint32_t)f2b(v.x) | ((uint32_t)f2b(v.y) << 16);
  uint32_t p1 = (uint32_t)f2b(v.z) | ((uint32_t)f2b(v.w) << 16);
  *(uint2*)(dst + i4) = make_uint2(p0, p1);
}

// ---------------- build xcT: [B,N,512] bf16 from x,y [B,256,N] f32 ----------------
__global__ __launch_bounds__(256) void k_build_xcT(const float* __restrict__ x,
                                                   const float* __restrict__ y,
                                                   unsigned short* __restrict__ xcT){
  __shared__ float t[32][33];
  int b = blockIdx.z;
  int n0 = blockIdx.x*32, c0 = blockIdx.y*32;
  int tx = threadIdx.x, ty = threadIdx.y;
  const float* src = (c0 < 256) ? (x + ((size_t)b*256 + c0)*N_)
                                : (y + ((size_t)b*256 + (c0-256))*N_);
  #pragma unroll
  for (int i = 0; i < 4; i++){
    int cl = ty*4 + i;
    t[cl][tx] = src[(size_t)cl*N_ + n0 + tx];
  }
  __syncthreads();
  #pragma unroll
  for (int i = 0; i < 4; i++){
    int nl = ty*4 + i;
    xcT[((size_t)b*N_ + n0 + nl)*512 + c0 + tx] = f2b(t[tx][nl]);
  }
}

// ---------------- feat mirrors: featT f32 [B,N,C] -> featbf [B,N,C] bf16 + featC [B,C,N] bf16 ----------------
__global__ __launch_bounds__(256) void k_featmir(const float* __restrict__ featT,
                                                 unsigned short* __restrict__ featbf,
                                                 unsigned short* __restrict__ featC){
  __shared__ float t[32][33];
  int b = blockIdx.z;
  int n0 = blockIdx.x*32, c0 = blockIdx.y*32;
  int tx = threadIdx.x, ty = threadIdx.y;
  #pragma unroll
  for (int i = 0; i < 4; i++){
    int nl = ty*4 + i;
    size_t m = (size_t)b*N_ + n0 + nl;
    float v = featT[m*256 + c0 + tx];
    t[nl][tx] = v;
    featbf[m*256 + c0 + tx] = f2b(v);
  }
  __syncthreads();
  #pragma unroll
  for (int i = 0; i < 4; i++){
    int cl = ty*4 + i;
    featC[((size_t)b*256 + c0 + cl)*(size_t)N_ + n0 + tx] = f2b(t[tx][cl]);
  }
}

// ---------------- combined saliency vector (fp64) ----------------
__global__ __launch_bounds__(512) void k_compute_u(const float* __restrict__ sal_w,
                                                   const float* __restrict__ proj_w,
                                                   const float* __restrict__ proj_b,
                                                   const float* __restrict__ sal_b,
                                                   double* __restrict__ u){
  int c2 = threadIdx.x; // 512 threads
  double acc = 0.0;
  for (int c = 0; c < 256; ++c)
    acc += (double)sal_w[c] * (double)proj_w[(size_t)c*512 + c2];
  u[c2] = acc;
  if (c2 == 0){
    double s0 = (double)sal_b[0];
    for (int c = 0; c < 256; ++c) s0 += (double)sal_w[c] * (double)proj_b[c];
    u[512] = s0;
  }
}

// ---------------- sal partials: part[cc][pix] = sum over 32 channels ----------------
__global__ __launch_bounds__(256) void k_sal_part(const float* __restrict__ x,
                                                  const float* __restrict__ y,
                                                  const double* __restrict__ u,
                                                  double* __restrict__ part){
  int pix = blockIdx.x*256 + threadIdx.x; // 32768
  int cc = blockIdx.y;                    // 16 chunks of 32 channels
  int b = pix >> 12, n = pix & 4095;
  int c0 = cc*32;
  const float* src = (c0 < 256) ? (x + ((size_t)b*256 + c0)*N_ + n)
                                : (y + ((size_t)b*256 + (c0-256))*N_ + n);
  const double* uu = u + c0;
  double acc = 0.0;
  #pragma unroll 8
  for (int c = 0; c < 32; ++c) acc += uu[c] * (double)src[(size_t)c*N_];
  part[(size_t)cc*32768 + pix] = acc;
}

// ---------------- sal reduce -> heat + mask counts ----------------
__global__ __launch_bounds__(256) void k_sal_red(const double* __restrict__ part,
                                                 const double* __restrict__ u,
                                                 float* __restrict__ heat,
                                                 int* __restrict__ counts){
  int pix = blockIdx.x*256 + threadIdx.x;
  int b = pix >> 12;
  double acc = u[512];
  #pragma unroll
  for (int cc = 0; cc < 16; cc++) acc += part[(size_t)cc*32768 + pix];
  float hf = (float)(1.0 / (1.0 + exp(-acc)));
  heat[pix] = hf;
  unsigned long long mfg = __ballot(hf >= 0.5f);
  unsigned long long mbg = __ballot(hf < 0.5f);
  if ((threadIdx.x & 63) == 0){
    atomicAdd(&counts[b*2+0], (int)__popcll(mfg));
    atomicAdd(&counts[b*2+1], (int)__popcll(mbg));
  }
}

// ---------------- bf16 MFMA GEMM:  out[M,N] = A[M,K] @ W[N,K]^T + bias ----------------
// 2-phase double-buffered; LDS 16B-unit XOR swizzle (rule #21).
// EPI 0: f32 out;  EPI 1: relu + bf16;  EPI 2: bf16;  EPI 3: bf16 transposed (vvT)
template<int EPI>
__global__ __launch_bounds__(256) void k_gemm_bt(
    const unsigned short* __restrict__ A, const unsigned short* __restrict__ W,
    const float* __restrict__ bias, void* __restrict__ out,
    int M, int N, int K){
  __shared__ unsigned short smem[2][2][128*64];   // [dbuf][A/B][tile] = 64KB
  int tid = threadIdx.x;
  int w = tid >> 6, l = tid & 63;
  int m0 = blockIdx.x * 128, n0 = blockIdx.y * 128;
  int wr = w >> 1, wc = w & 1;
  int lr = l & 15, lk = l >> 4;
  f32x4 acc[4][4] = {};
  int nt = K >> 6;
  #pragma unroll
  for (int i = 0; i < 4; i++){
    int idx = i*256 + tid;
    int row = idx >> 3, su = ((idx & 7) ^ (row & 7))*8;
    gload_lds16(A + (size_t)(m0+row)*K + su, &smem[0][0][idx*8]);
    gload_lds16(W + (size_t)(n0+row)*K + su, &smem[0][1][idx*8]);
  }
  __syncthreads();
  for (int t = 0; t < nt; ++t){
    int cur = t & 1;
    if (t + 1 < nt){
      int k0 = (t + 1) << 6;
      #pragma unroll
      for (int i = 0; i < 4; i++){
        int idx = i*256 + tid;
        int row = idx >> 3, su = ((idx & 7) ^ (row & 7))*8;
        gload_lds16(A + (size_t)(m0+row)*K + k0 + su, &smem[cur^1][0][idx*8]);
        gload_lds16(W + (size_t)(n0+row)*K + k0 + su, &smem[cur^1][1][idx*8]);
      }
    }
    const unsigned short* ldsA = smem[cur][0];
    const unsigned short* ldsB = smem[cur][1];
    #pragma unroll
    for (int kk = 0; kk < 2; kk++){
      v8bf af[4], bfr[4];
      #pragma unroll
      for (int f = 0; f < 4; f++){
        int ra = wr*64 + f*16 + lr;
        int rb2 = wc*64 + f*16 + lr;
        int u = kk*4 + lk;
        af[f]  = *(const v8bf*)(&ldsA[ra*64 + ((u ^ (ra&7))<<3)]);
        bfr[f] = *(const v8bf*)(&ldsB[rb2*64 + ((u ^ (rb2&7))<<3)]);
      }
      #pragma unroll
      for (int fi = 0; fi < 4; fi++)
        #pragma unroll
        for (int fj = 0; fj < 4; fj++)
          acc[fi][fj] = __builtin_amdgcn_mfma_f32_16x16x32_bf16(af[fi], bfr[fj], acc[fi][fj], 0, 0, 0);
    }
    __syncthreads();
  }
  if (EPI == 1 || EPI == 2){
    unsigned short* st = &smem[0][0][0];
    #pragma unroll
    for (int fj = 0; fj < 4; fj++){
      int col = wc*64 + fj*16 + lr;
      float bv = bias[n0 + col];
      #pragma unroll
      for (int fi = 0; fi < 4; fi++){
        int rl = wr*64 + fi*16 + lk*4;
        #pragma unroll
        for (int r = 0; r < 4; r++){
          float v = acc[fi][fj][r] + bv;
          if (EPI == 1) v = fmaxf(v, 0.f);
          st[(rl + r)*136 + col] = f2b(v);
        }
      }
    }
    __syncthreads();
    #pragma unroll
    for (int it = 0; it < 8; it++){
      int idx = it*256 + tid;
      int row = idx >> 4, c8 = (idx & 15)*8;
      *(uint4*)((unsigned short*)out + (size_t)(m0+row)*N + n0 + c8)
          = *(const uint4*)&st[row*136 + c8];
    }
  } else {
    #pragma unroll
    for (int fj = 0; fj < 4; fj++){
      int col = n0 + wc*64 + fj*16 + lr;
      float bv = bias[col];
      #pragma unroll
      for (int fi = 0; fi < 4; fi++){
        int rb = m0 + wr*64 + fi*16 + lk*4;
        #pragma unroll
        for (int r = 0; r < 4; r++){
          float v = acc[fi][fj][r] + bv;
          if (EPI == 3){
            int row = rb + r;
            ((unsigned short*)out)[((size_t)(row>>6)*256 + col)*64 + (row&63)] = f2b(v);
          } else {
            ((float*)out)[(size_t)(rb + r)*N + col] = v;
          }
        }
      }
    }
  }
}

// ---------------- fused FFN: out = relu(A@W1^T+b1)@W2^T + b2  (per 128-row tile) ----------------
// A [128][256] persistent in LDS; 16 F-chunks of 64: h chunk kept in LDS only.
// Same 16x16x32 fragment + 16B-unit XOR swizzle math as k_gemm_bt (verified).
__global__ __launch_bounds__(256) void k_ffn(
    const unsigned short* __restrict__ qb, const unsigned short* __restrict__ W1g,
    const float* __restrict__ b1g, const unsigned short* __restrict__ W2g,
    const float* __restrict__ b2g, unsigned short* __restrict__ outb){
  __shared__ unsigned short smem[73728];  // 144 KB
  unsigned short* sA  = smem;             // [128][256] 64KB
  unsigned short* sW1 = smem + 32768;     // [64][256]  32KB
  unsigned short* sW2 = smem + 49152;     // [256][64]  32KB
  unsigned short* sH  = smem + 65536;     // [128][64]  16KB
  int tid = threadIdx.x, w = tid >> 6, l = tid & 63;
  int m0 = blockIdx.x * 128;
  int wrM = w >> 1, wcF = w & 1;          // A-phase: M-half x F-half(32); B-phase: M-half x C-half(128)
  int lr = l & 15, lk = l >> 4;
  // stage A (once)
  #pragma unroll
  for (int i = 0; i < 16; i++){
    int idx = i*256 + tid;                 // 128 rows x 32 units
    int row = idx >> 5, g = idx & 31;
    int su = (g & 24) | ((g & 7) ^ (row & 7));
    gload_lds16(qb + (size_t)(m0+row)*256 + su*8, &sA[idx*8]);
  }
  f32x4 acc[4][8] = {};
  for (int cc = 0; cc < 16; ++cc){
    int f0 = cc*64;
    #pragma unroll
    for (int i = 0; i < 8; i++){           // W1 chunk [64][256]
      int idx = i*256 + tid;
      int row = idx >> 5, g = idx & 31;
      int su = (g & 24) | ((g & 7) ^ (row & 7));
      gload_lds16(W1g + (size_t)(f0+row)*256 + su*8, &sW1[idx*8]);
    }
    #pragma unroll
    for (int i = 0; i < 8; i++){           // W2 chunk [256][64]
      int idx = i*256 + tid;
      int row = idx >> 3, g = idx & 7;
      int su = g ^ (row & 7);
      gload_lds16(W2g + (size_t)row*1024 + f0 + su*8, &sW2[idx*8]);
    }
    __syncthreads();
    // phase A: h[128,64] = A @ W1chunk^T
    f32x4 hacc[4][2] = {};
    #pragma unroll
    for (int ks = 0; ks < 8; ks++){
      v8bf af[4], bf[2];
      int g = ks*4 + lk;
      #pragma unroll
      for (int f = 0; f < 4; f++){
        int ra = wrM*64 + f*16 + lr;
        af[f] = *(const v8bf*)&sA[ra*256 + (((g & 24) | ((g & 7) ^ (ra & 7)))<<3)];
      }
      #pragma unroll
      for (int f = 0; f < 2; f++){
        int rf = wcF*32 + f*16 + lr;
        bf[f] = *(const v8bf*)&sW1[rf*256 + (((g & 24) | ((g & 7) ^ (rf & 7)))<<3)];
      }
      #pragma unroll
      for (int fi = 0; fi < 4; fi++)
        #pragma unroll
        for (int fj = 0; fj < 2; fj++)
          hacc[fi][fj] = __builtin_amdgcn_mfma_f32_16x16x32_bf16(af[fi], bf[fj], hacc[fi][fj], 0, 0, 0);
    }
    // bias + relu -> sH (bf16, swizzled)
    #pragma unroll
    for (int fj = 0; fj < 2; fj++){
      int fc = wcF*32 + fj*16 + lr;
      float b1v = b1g[f0 + fc];
      #pragma unroll
      for (int fi = 0; fi < 4; fi++){
        int mr0 = wrM*64 + fi*16 + lk*4;
        #pragma unroll
        for (int r = 0; r < 4; r++){
          float v = fmaxf(hacc[fi][fj][r] + b1v, 0.f);
          int mr = mr0 + r;
          sH[mr*64 + (((fc >> 3) ^ (mr & 7))<<3) + (fc & 7)] = f2b(v);
        }
      }
    }
    __syncthreads();
    // phase B: out += h @ W2chunk^T
    #pragma unroll
    for (int ks2 = 0; ks2 < 2; ks2++){
      v8bf ha[4], wb[8];
      int g = ks2*4 + lk;
      #pragma unroll
      for (int f = 0; f < 4; f++){
        int rh = wrM*64 + f*16 + lr;
        ha[f] = *(const v8bf*)&sH[rh*64 + ((g ^ (rh & 7))<<3)];
      }
      #pragma unroll
      for (int f = 0; f < 8; f++){
        int rc = wcF*128 + f*16 + lr;
        wb[f] = *(const v8bf*)&sW2[rc*64 + ((g ^ (rc & 7))<<3)];
      }
      #pragma unroll
      for (int fi = 0; fi < 4; fi++)
        #pragma unroll
        for (int fc = 0; fc < 8; fc++)
          acc[fi][fc] = __builtin_amdgcn_mfma_f32_16x16x32_bf16(ha[fi], wb[fc], acc[fi][fc], 0, 0, 0);
    }
    __syncthreads();
  }
  // epilogue: bias, stage to LDS (pitch 264), coalesced stores
  unsigned short* st = smem;
  #pragma unroll
  for (int fc = 0; fc < 8; fc++){
    int col = wcF*128 + fc*16 + lr;
    float bv = b2g[col];
    #pragma unroll
    for (int fi = 0; fi < 4; fi++){
      int rl = wrM*64 + fi*16 + lk*4;
      #pragma unroll
      for (int r = 0; r < 4; r++)
        st[(rl + r)*264 + col] = f2b(acc[fi][fc][r] + bv);
    }
  }
  __syncthreads();
  #pragma unroll
  for (int it = 0; it < 16; it++){
    int idx = it*256 + tid;               // 128 rows x 32 units
    int row = idx >> 5, c8 = (idx & 31)*8;
    *(uint4*)(outb + (size_t)(m0+row)*256 + c8) = *(const uint4*)&st[row*264 + c8];
  }
}

// ---------------- swh[b][side][k][n] = (g*hm + sb)*hm  (bf16) ----------------
__global__ __launch_bounds__(256) void k_swh(const float* __restrict__ g_all,
                                             const float* __restrict__ heat,
                                             const float* __restrict__ soft_b,
                                             unsigned short* __restrict__ swh){
  __shared__ float gl[64*129];
  __shared__ float hml[64];
  int tid = threadIdx.x;
  int blk = blockIdx.x;
  size_t m0 = (size_t)blk*64;
  int b = (int)(m0 >> 12), n0 = (int)(m0 & 4095);
  #pragma unroll
  for (int i = 0; i < 32; i++){
    int idx = i*256 + tid;
    int row = idx >> 7, col = idx & 127;
    gl[row*129 + col] = g_all[(m0 + row)*128 + col];
  }
  if (tid < 64) hml[tid] = heat[(size_t)b*4096 + n0 + tid];
  __syncthreads();
  int k = tid >> 2, j0 = (tid & 3)*16;
  #pragma unroll
  for (int s = 0; s < 2; s++){
    float sb = soft_b[s*64 + k];
    unsigned short vals[16];
    #pragma unroll
    for (int j = 0; j < 16; j++){
      int n = j0 + j;
      float h = hml[n];
      float hm = s ? (1.0f - h) : h;
      vals[j] = f2b((gl[n*129 + s*64 + k]*hm + sb)*hm);
    }
    unsigned short* dst = swh + (((size_t)b*2 + s)*64 + k)*4096 + n0 + j0;
    uint4 o0, o1;
    o0.x = vals[0] | ((uint32_t)vals[1]<<16);  o0.y = vals[2] | ((uint32_t)vals[3]<<16);
    o0.z = vals[4] | ((uint32_t)vals[5]<<16);  o0.w = vals[6] | ((uint32_t)vals[7]<<16);
    o1.x = vals[8] | ((uint32_t)vals[9]<<16);  o1.y = vals[10]| ((uint32_t)vals[11]<<16);
    o1.z = vals[12]| ((uint32_t)vals[13]<<16); o1.w = vals[14]| ((uint32_t)vals[15]<<16);
    *(uint4*)dst = o0;
    *(uint4*)(dst + 8) = o1;
  }
}

// ---------------- pool GEMM (split-K): pp[kc][b][128][256] = swh[b] @ featC[b]^T ----------------
__global__ __launch_bounds__(256) void k_poolgemm(
    const unsigned short* __restrict__ swh, const unsigned short* __restrict__ featC,
    float* __restrict__ pp){
  __shared__ unsigned short ldsA[128*64];
  __shared__ unsigned short ldsB[128*64];
  int tid = threadIdx.x;
  int w = tid >> 6, l = tid & 63;
  int kc = blockIdx.x, nt = blockIdx.y, b = blockIdx.z;
  int wr = w >> 1, wc = w & 1;
  int lr = l & 15, lk = l >> 4;
  const unsigned short* A = swh  + (size_t)b*128*4096 + kc*512;
  const unsigned short* W = featC + ((size_t)b*256 + nt*128)*4096 + kc*512;
  f32x4 acc[4][4] = {};
  for (int k0 = 0; k0 < 512; k0 += 64){
    #pragma unroll
    for (int i = 0; i < 4; i++){
      int idx = i*256 + tid;
      int row = idx >> 3, su = (idx & 7) ^ (row & 7);
      gload_lds16(A + (size_t)row*4096 + k0 + su*8, &ldsA[idx*8]);
    }
    #pragma unroll
    for (int i = 0; i < 4; i++){
      int idx = i*256 + tid;
      int row = idx >> 3, su = (idx & 7) ^ (row & 7);
      gload_lds16(W + (size_t)row*4096 + k0 + su*8, &ldsB[idx*8]);
    }
    __syncthreads();
    #pragma unroll
    for (int kk = 0; kk < 2; kk++){
      v8bf af[4], bfr[4];
      #pragma unroll
      for (int f = 0; f < 4; f++){
        int ra = wr*64 + f*16 + lr;
        int rb2 = wc*64 + f*16 + lr;
        int u = kk*4 + lk;
        af[f]  = *(const v8bf*)(&ldsA[ra*64 + ((u ^ (ra&7))<<3)]);
        bfr[f] = *(const v8bf*)(&ldsB[rb2*64 + ((u ^ (rb2&7))<<3)]);
      }
      #pragma unroll
      for (int fi = 0; fi < 4; fi++)
        #pragma unroll
        for (int fj = 0; fj < 4; fj++)
          acc[fi][fj] = __builtin_amdgcn_mfma_f32_16x16x32_bf16(af[fi], bfr[fj], acc[fi][fj], 0, 0, 0);
    }
    __syncthreads();
  }
  float* dst = pp + ((size_t)kc*8 + b)*128*256;
  #pragma unroll
  for (int fj = 0; fj < 4; fj++){
    int col = nt*128 + wc*64 + fj*16 + lr;
    #pragma unroll
    for (int fi = 0; fi < 4; fi++){
      int rb = wr*64 + fi*16 + lk*4;
      #pragma unroll
      for (int r = 0; r < 4; r++)
        dst[(size_t)(rb + r)*256 + col] = acc[fi][fj][r];
    }
  }
}

// ---------------- reduce split-K partials -> pool_bf_s[side][b*64+k][c] bf16 ----------------
__global__ __launch_bounds__(256) void k_pool2b(const float* __restrict__ pp,
                                                unsigned short* __restrict__ pool_bf_s){
  int bk = blockIdx.x, side = blockIdx.y, c = threadIdx.x;
  int b = bk >> 6, k = bk & 63;
  float s = 0.f;
  #pragma unroll
  for (int kc = 0; kc < 8; kc++)
    s += pp[(((size_t)kc*8 + b)*128 + side*64 + k)*256 + c];
  pool_bf_s[((size_t)side*512 + bk)*256 + c] = f2b(s);
}

// ---------------- MFMA attention: 64 q-rows/block, 8 heads, 64 keys, DH=32 ----------------
__global__ __launch_bounds__(256) void k_attn2(
    const unsigned short* __restrict__ qq, const unsigned short* __restrict__ kk,
    const unsigned short* __restrict__ vvT, unsigned short* __restrict__ obf){
  __shared__ unsigned short sk[64*256];
  __shared__ unsigned short svT[256*64];
  __shared__ unsigned short sp[4][16*64];
  __shared__ unsigned short sow[4][16*32];
  int tid = threadIdx.x, w = tid >> 6, l = tid & 63;
  int blk = blockIdx.x, b = blk >> 6;
  int l15 = l & 15, lg = l >> 4;
  const uint4* ksrc = (const uint4*)(kk + (size_t)b*64*256);
  #pragma unroll
  for (int i = 0; i < 8; i++){
    int u = i*256 + tid;
    int row = u >> 5, j = u & 31;
    *(uint4*)&sk[row*256 + ((j ^ (row&7))<<3)] = ksrc[u];
  }
  const uint4* vsrc = (const uint4*)(vvT + (size_t)b*256*64);
  #pragma unroll
  for (int i = 0; i < 8; i++){
    int u = i*256 + tid;
    int row = u >> 3, j = u & 7;
    *(uint4*)&svT[row*64 + ((j ^ (row&7))<<3)] = vsrc[u];
  }
  __syncthreads();
  size_t qrow = (size_t)blk*64 + w*16 + l15;
  for (int h = 0; h < 8; h++){
    v8bf aq = *(const v8bf*)(qq + qrow*256 + h*32 + lg*8);
    f32x4 s[4];
    #pragma unroll
    for (int kt = 0; kt < 4; kt++){
      int row = kt*16 + l15;
      v8bf bk = *(const v8bf*)&sk[row*256 + (((h*4 + lg) ^ (row&7))<<3)];
      f32x4 z = {};
      s[kt] = __builtin_amdgcn_mfma_f32_16x16x32_bf16(aq, bk, z, 0, 0, 0);
    }
    #pragma unroll
    for (int r = 0; r < 4; r++){
      float v0 = s[0][r]*SCALE_, v1 = s[1][r]*SCALE_;
      float v2 = s[2][r]*SCALE_, v3 = s[3][r]*SCALE_;
      float mx = fmaxf(fmaxf(v0, v1), fmaxf(v2, v3));
      mx = fmaxf(mx, __shfl_xor(mx, 1));
      mx = fmaxf(mx, __shfl_xor(mx, 2));
      mx = fmaxf(mx, __shfl_xor(mx, 4));
      mx = fmaxf(mx, __shfl_xor(mx, 8));
      float e0 = __expf(v0-mx), e1 = __expf(v1-mx);
      float e2 = __expf(v2-mx), e3 = __expf(v3-mx);
      float sum = e0+e1+e2+e3;
      sum += __shfl_xor(sum, 1); sum += __shfl_xor(sum, 2);
      sum += __shfl_xor(sum, 4); sum += __shfl_xor(sum, 8);
      float inv = 1.0f/sum;
      s[0][r] = e0*inv; s[1][r] = e1*inv; s[2][r] = e2*inv; s[3][r] = e3*inv;
    }
    #pragma unroll
    for (int kt = 0; kt < 4; kt++){
      int colu = kt*2 + (l15>>3);
      #pragma unroll
      for (int r = 0; r < 4; r++){
        int row = lg*4 + r;
        sp[w][row*64 + ((colu ^ (row&7))<<3) + (l&7)] = f2b(s[kt][r]);
      }
    }
    f32x4 o[2] = {};
    #pragma unroll
    for (int k2 = 0; k2 < 2; k2++){
      v8bf pa = *(const v8bf*)&sp[w][l15*64 + (((k2*4 + lg) ^ (l15&7))<<3)];
      #pragma unroll
      for (int dt = 0; dt < 2; dt++){
        int vrow = h*32 + dt*16 + l15;
        v8bf bv = *(const v8bf*)&svT[vrow*64 + (((k2*4 + lg) ^ (vrow&7))<<3)];
        o[dt] = __builtin_amdgcn_mfma_f32_16x16x32_bf16(pa, bv, o[dt], 0, 0, 0);
      }
    }
    #pragma unroll
    for (int dt = 0; dt < 2; dt++)
      #pragma unroll
      for (int r = 0; r < 4; r++)
        sow[w][(lg*4 + r)*32 + dt*16 + l15] = f2b(o[dt][r]);
    uint4 ov = *(const uint4*)&sow[w][l15*32 + lg*8];
    *(uint4*)(obf + qrow*256 + h*32 + lg*8) = ov;
  }
}

// ---------------- residual(bf16 or f32) + bf16 delta -> LayerNorm -> bf16 ----------------
template<int RF32>
__global__ __launch_bounds__(256) void k_ln2(
    const void* __restrict__ resid, const unsigned short* __restrict__ delta,
    const float* __restrict__ g, const float* __restrict__ bta,
    unsigned short* __restrict__ qout){
  int wv = threadIdx.x >> 6, l = threadIdx.x & 63;
  size_t m = (size_t)blockIdx.x*4 + wv;
  uint2 dv = *(const uint2*)(delta + m*256 + l*4);
  float d0 = b2f((unsigned short)(dv.x & 0xffff)), d1 = b2f((unsigned short)(dv.x >> 16));
  float d2 = b2f((unsigned short)(dv.y & 0xffff)), d3 = b2f((unsigned short)(dv.y >> 16));
  float x0, x1, x2, x3;
  if (RF32){
    float4 rv = *(const float4*)((const float*)resid + m*256 + l*4);
    x0 = rv.x+d0; x1 = rv.y+d1; x2 = rv.z+d2; x3 = rv.w+d3;
  } else {
    uint2 rv = *(const uint2*)((const unsigned short*)resid + m*256 + l*4);
    x0 = b2f((unsigned short)(rv.x & 0xffff)) + d0;
    x1 = b2f((unsigned short)(rv.x >> 16)) + d1;
    x2 = b2f((unsigned short)(rv.y & 0xffff)) + d2;
    x3 = b2f((unsigned short)(rv.y >> 16)) + d3;
  }
  float s = x0+x1+x2+x3;
  float ss = x0*x0+x1*x1+x2*x2+x3*x3;
  #pragma unroll
  for (int off = 32; off; off >>= 1){
    s  += __shfl_xor(s, off);
    ss += __shfl_xor(ss, off);
  }
  float mean = s * (1.0f/256.0f);
  float var = ss * (1.0f/256.0f) - mean*mean;
  float rstd = 1.0f / sqrtf(var + 1e-5f);
  float4 gv = *(const float4*)(g + l*4);
  float4 bv = *(const float4*)(bta + l*4);
  float y0 = (x0-mean)*rstd*gv.x + bv.x;
  float y1 = (x1-mean)*rstd*gv.y + bv.y;
  float y2 = (x2-mean)*rstd*gv.z + bv.z;
  float y3 = (x3-mean)*rstd*gv.w + bv.w;
  uint32_t p0 = (uint32_t)f2b(y0) | ((uint32_t)f2b(y1)<<16);
  uint32_t p1 = (uint32_t)f2b(y2) | ((uint32_t)f2b(y3)<<16);
  *(uint2*)(qout + m*256 + l*4) = make_uint2(p0,p1);
}

// ---------------- final select + transpose [B,N,C] -> [B,C,N] ----------------
__global__ __launch_bounds__(256) void k_select(
    const unsigned short* __restrict__ qA, const unsigned short* __restrict__ qB,
    const float* __restrict__ featT, const float* __restrict__ heat,
    const int* __restrict__ counts, float* __restrict__ out){
  __shared__ float t[32][33];
  int b = blockIdx.z;
  int n0 = blockIdx.x*32, c0 = blockIdx.y*32;
  int tx = threadIdx.x, ty = threadIdx.y;
  bool valid = (counts[b*2] > 0) && (counts[b*2+1] > 0);
  #pragma unroll
  for (int i = 0; i < 4; i++){
    int nl = ty*4+i;
    size_t m = (size_t)b*4096 + n0 + nl;
    float v;
    if (!valid) v = featT[m*256 + c0 + tx];
    else {
      bool fg = heat[(size_t)b*4096 + n0 + nl] >= 0.5f;
      v = fg ? b2f(qA[m*256 + c0 + tx]) : b2f(qB[m*256 + c0 + tx]);
    }
    t[nl][tx] = v;
  }
  __syncthreads();
  #pragma unroll
  for (int i = 0; i < 4; i++){
    int cl = ty*4+i;
    out[((size_t)b*256 + c0 + cl)*4096 + n0 + tx] = t[tx][cl];
  }
}

extern "C" void kernel_launch(void* const* d_in, const int* in_sizes, int n_in,
                              void* d_out, int out_size, void* d_ws, size_t ws_size,
                              hipStream_t stream){
  const float* x         = (const float*)d_in[0];
  const float* y         = (const float*)d_in[1];
  const float* proj_w    = (const float*)d_in[2];
  const float* proj_b    = (const float*)d_in[3];
  const float* sal_w     = (const float*)d_in[4];
  const float* sal_b     = (const float*)d_in[5];
  const float* soft_w    = (const float*)d_in[6];
  const float* soft_b    = (const float*)d_in[7];
  const float* attn_in_w = (const float*)d_in[8];
  const float* attn_in_b = (const float*)d_in[9];
  const float* attn_out_w= (const float*)d_in[10];
  const float* attn_out_b= (const float*)d_in[11];
  const float* n1_g      = (const float*)d_in[12];
  const float* n1_b      = (const float*)d_in[13];
  const float* ffn_w1    = (const float*)d_in[14];
  const float* ffn_b1    = (const float*)d_in[15];
  const float* ffn_w2    = (const float*)d_in[16];
  const float* ffn_b2    = (const float*)d_in[17];
  const float* n2_g      = (const float*)d_in[18];
  const float* n2_b      = (const float*)d_in[19];
  float* out = (float*)d_out;

  // ---- workspace layout (~204 MB; proven limit is >= 263 MB) ----
  char* p = (char*)d_ws;
  auto alloc = [&](size_t bytes){ char* r = p; p += (bytes + 255) & ~(size_t)255; return r; };
  unsigned short* hbf   = (unsigned short*)alloc((size_t)M_*FF_*2);
  unsigned short* xcT   = hbf;            // [M,512] bf16, dead before layers
  unsigned short* qq_bf = hbf;            // [M,C] bf16, consumed by attn
  float* featT = (float*)alloc((size_t)M_*C_*4);
  unsigned short* qAb = (unsigned short*)alloc((size_t)M_*C_*2);
  unsigned short* swh = qAb;              // dead before side-0 n1
  unsigned short* qBb = (unsigned short*)alloc((size_t)M_*C_*2);
  unsigned short* obf = (unsigned short*)alloc((size_t)M_*C_*2);
  unsigned short* featC = obf;            // dead before first attn
  unsigned short* featbf = (unsigned short*)alloc((size_t)M_*C_*2);
  unsigned short* tmpb = (unsigned short*)alloc((size_t)M_*C_*2);
  float* g_all = (float*)tmpb;            // dead before layers
  float* pp    = (float*)alloc((size_t)8*8*128*256*4);   // 8.4MB; also hosts sal partials early
  double* salp = (double*)pp;             // 16*32768*8 = 4MB, dead before poolgemm
  unsigned short* pool_bf_s = (unsigned short*)alloc((size_t)2*512*256*2);
  unsigned short* kk_bf = (unsigned short*)alloc((size_t)B_*K_*C_*2);
  unsigned short* vvT_bf= (unsigned short*)alloc((size_t)B_*C_*K_*2);
  float* heat = (float*)alloc((size_t)B_*N_*4);
  double* u   = (double*)alloc(513*8);
  int* counts = (int*)alloc(64);
  float* zbias = (float*)alloc(512);
  unsigned short* projw_bf = (unsigned short*)alloc((size_t)C_*512*2);
  unsigned short* aiw_bf = (unsigned short*)alloc((size_t)2*L_*768*C_*2);
  unsigned short* aow_bf = (unsigned short*)alloc((size_t)2*L_*C_*C_*2);
  unsigned short* f1w_bf = (unsigned short*)alloc((size_t)2*L_*FF_*C_*2);
  unsigned short* f2w_bf = (unsigned short*)alloc((size_t)2*L_*C_*FF_*2);
  unsigned short* sw2_bf = (unsigned short*)alloc((size_t)2*K_*C_*2);

  hipMemsetAsync(counts, 0, 64, stream);
  hipMemsetAsync(zbias, 0, 512, stream);
  k_compute_u<<<1, 512, 0, stream>>>(sal_w, proj_w, proj_b, sal_b, u);
  k_sal_part<<<dim3(128, 16), 256, 0, stream>>>(x, y, u, salp);
  k_sal_red<<<128, 256, 0, stream>>>(salp, u, heat, counts);

  auto conv = [&](const float* s, unsigned short* d, size_t n){
    k_f32_to_bf16<<<(unsigned)((n/4 + 255)/256), 256, 0, stream>>>(s, d, (int)n);
  };
  conv(proj_w,     projw_bf, (size_t)C_*512);
  conv(attn_in_w,  aiw_bf,   (size_t)2*L_*768*C_);
  conv(attn_out_w, aow_bf,   (size_t)2*L_*C_*C_);
  conv(ffn_w1,     f1w_bf,   (size_t)2*L_*FF_*C_);
  conv(ffn_w2,     f2w_bf,   (size_t)2*L_*C_*FF_);
  conv(soft_w,     sw2_bf,   (size_t)2*K_*C_);

  k_build_xcT<<<dim3(N_/32, 512/32, B_), dim3(32,8), 0, stream>>>(x, y, xcT);
  k_gemm_bt<0><<<dim3(M_/128, C_/128), 256, 0, stream>>>(xcT, projw_bf, proj_b, featT, M_, C_, 512);
  k_featmir<<<dim3(N_/32, C_/32, B_), dim3(32,8), 0, stream>>>(featT, featbf, featC);

  // sw/pool pipeline (both sides at once)
  k_gemm_bt<0><<<dim3(M_/128, 1), 256, 0, stream>>>(featbf, sw2_bf, zbias, g_all, M_, 128, C_);
  k_swh<<<M_/64, 256, 0, stream>>>(g_all, heat, soft_b, swh);
  k_poolgemm<<<dim3(8, 2, B_), 256, 0, stream>>>(swh, featC, pp);
  k_pool2b<<<dim3(512, 2), 256, 0, stream>>>(pp, pool_bf_s);

  for (int side = 0; side < 2; ++side){
    unsigned short* qb = side ? qBb : qAb;
    const unsigned short* poolS = pool_bf_s + (size_t)side*512*256;
    for (int lyr = 0; lyr < L_; ++lyr){
      int sl = side*L_ + lyr;
      const unsigned short* iw = aiw_bf + (size_t)sl*768*C_;
      const float* ib = attn_in_b + (size_t)sl*768;
      const unsigned short* qin = (lyr == 0) ? featbf : qb;
      k_gemm_bt<2><<<dim3(M_/128, C_/128), 256, 0, stream>>>(qin, iw, ib, qq_bf, M_, C_, C_);
      k_gemm_bt<2><<<dim3((B_*K_)/128, C_/128), 256, 0, stream>>>(poolS, iw + 256*C_, ib + 256, kk_bf, B_*K_, C_, C_);
      k_gemm_bt<3><<<dim3((B_*K_)/128, C_/128), 256, 0, stream>>>(poolS, iw + 512*C_, ib + 512, vvT_bf, B_*K_, C_, C_);
      k_attn2<<<M_/64, 256, 0, stream>>>(qq_bf, kk_bf, vvT_bf, obf);
      k_gemm_bt<2><<<dim3(M_/128, C_/128), 256, 0, stream>>>(obf, aow_bf + (size_t)sl*C_*C_, attn_out_b + (size_t)sl*C_, tmpb, M_, C_, C_);
      if (lyr == 0)
        k_ln2<1><<<M_/4, 256, 0, stream>>>(featT, tmpb, n1_g + (size_t)sl*C_, n1_b + (size_t)sl*C_, qb);
      else
        k_ln2<0><<<M_/4, 256, 0, stream>>>(qb, tmpb, n1_g + (size_t)sl*C_, n1_b + (size_t)sl*C_, qb);
      k_ffn<<<M_/128, 256, 0, stream>>>(qb, f1w_bf + (size_t)sl*FF_*C_, ffn_b1 + (size_t)sl*FF_,
                                        f2w_bf + (size_t)sl*C_*FF_, ffn_b2 + (size_t)sl*C_, tmpb);
      k_ln2<0><<<M_/4, 256, 0, stream>>>(qb, tmpb, n2_g + (size_t)sl*C_, n2_b + (size_t)sl*C_, qb);
    }
  }
  k_select<<<dim3(N_/32, C_/32, B_), dim3(32,8), 0, stream>>>(qAb, qBb, featT, heat, counts, out);
}

// Round 8
// 855.376 us; speedup vs baseline: 1.1348x; 1.1348x over previous
//
#include <hip/hip_runtime.h>
#include <stdint.h>

#define B_ 8
#define C_ 256
#define N_ 4096
#define K_ 64
#define NH_ 8
#define FF_ 1024
#define L_ 3
#define M_ (B_*N_)
#define SCALE_ 0.17677669529663687f

typedef float f32x4 __attribute__((ext_vector_type(4)));
typedef __bf16 v8bf __attribute__((ext_vector_type(8)));

__device__ __forceinline__ float b2f(unsigned short h){
  union { uint32_t u; float f; } v; v.u = ((uint32_t)h) << 16; return v.f;
}
__device__ __forceinline__ unsigned short f2b(float f){
  union { float f; uint32_t u; } v; v.f = f;
  uint32_t r = v.u + 0x7fffu + ((v.u >> 16) & 1u);
  return (unsigned short)(r >> 16);
}
__device__ __forceinline__ void gload_lds16(const void* g, void* l){
  __builtin_amdgcn_global_load_lds(
      (const __attribute__((address_space(1))) unsigned int*)g,
      (__attribute__((address_space(3))) unsigned int*)l, 16, 0, 0);
}

// ---------------- fp32 -> bf16 convert ----------------
__global__ __launch_bounds__(256) void k_f32_to_bf16(const float* __restrict__ src,
                                                     unsigned short* __restrict__ dst, int n){
  int i4 = (blockIdx.x*256 + threadIdx.x)*4;
  if (i4 >= n) return;
  float4 v = *(const float4*)(src + i4);
  uint32_t p0 = (uint32_t)f2b(v.x) | ((uint32_t)f2b(v.y) << 16);
  uint32_t p1 = (uint32_t)f2b(v.z) | ((uint32_t)f2b(v.w) << 16);
  *(uint2*)(dst + i4) = make_uint2(p0, p1);
}

// ---------------- build xcT: [B,N,512] bf16 from x,y [B,256,N] f32 ----------------
__global__ __launch_bounds__(256) void k_build_xcT(const float* __restrict__ x,
                                                   const float* __restrict__ y,
                                                   unsigned short* __restrict__ xcT){
  __shared__ float t[32][33];
  int b = blockIdx.z;
  int n0 = blockIdx.x*32, c0 = blockIdx.y*32;
  int tx = threadIdx.x, ty = threadIdx.y;
  const float* src = (c0 < 256) ? (x + ((size_t)b*256 + c0)*N_)
                                : (y + ((size_t)b*256 + (c0-256))*N_);
  #pragma unroll
  for (int i = 0; i < 4; i++){
    int cl = ty*4 + i;
    t[cl][tx] = src[(size_t)cl*N_ + n0 + tx];
  }
  __syncthreads();
  #pragma unroll
  for (int i = 0; i < 4; i++){
    int nl = ty*4 + i;
    xcT[((size_t)b*N_ + n0 + nl)*512 + c0 + tx] = f2b(t[tx][nl]);
  }
}

// ---------------- feat mirrors: featT f32 [B,N,C] -> featbf [B,N,C] bf16 + featC [B,C,N] bf16 ----------------
__global__ __launch_bounds__(256) void k_featmir(const float* __restrict__ featT,
                                                 unsigned short* __restrict__ featbf,
                                                 unsigned short* __restrict__ featC){
  __shared__ float t[32][33];
  int b = blockIdx.z;
  int n0 = blockIdx.x*32, c0 = blockIdx.y*32;
  int tx = threadIdx.x, ty = threadIdx.y;
  #pragma unroll
  for (int i = 0; i < 4; i++){
    int nl = ty*4 + i;
    size_t m = (size_t)b*N_ + n0 + nl;
    float v = featT[m*256 + c0 + tx];
    t[nl][tx] = v;
    featbf[m*256 + c0 + tx] = f2b(v);
  }
  __syncthreads();
  #pragma unroll
  for (int i = 0; i < 4; i++){
    int cl = ty*4 + i;
    featC[((size_t)b*256 + c0 + cl)*(size_t)N_ + n0 + tx] = f2b(t[tx][cl]);
  }
}

// ---------------- combined saliency vector (fp64) ----------------
__global__ __launch_bounds__(512) void k_compute_u(const float* __restrict__ sal_w,
                                                   const float* __restrict__ proj_w,
                                                   const float* __restrict__ proj_b,
                                                   const float* __restrict__ sal_b,
                                                   double* __restrict__ u){
  int c2 = threadIdx.x; // 512 threads
  double acc = 0.0;
  for (int c = 0; c < 256; ++c)
    acc += (double)sal_w[c] * (double)proj_w[(size_t)c*512 + c2];
  u[c2] = acc;
  if (c2 == 0){
    double s0 = (double)sal_b[0];
    for (int c = 0; c < 256; ++c) s0 += (double)sal_w[c] * (double)proj_b[c];
    u[512] = s0;
  }
}

// ---------------- sal partials: part[cc][pix] = sum over 32 channels ----------------
__global__ __launch_bounds__(256) void k_sal_part(const float* __restrict__ x,
                                                  const float* __restrict__ y,
                                                  const double* __restrict__ u,
                                                  double* __restrict__ part){
  int pix = blockIdx.x*256 + threadIdx.x; // 32768
  int cc = blockIdx.y;                    // 16 chunks of 32 channels
  int b = pix >> 12, n = pix & 4095;
  int c0 = cc*32;
  const float* src = (c0 < 256) ? (x + ((size_t)b*256 + c0)*N_ + n)
                                : (y + ((size_t)b*256 + (c0-256))*N_ + n);
  const double* uu = u + c0;
  double acc = 0.0;
  #pragma unroll 8
  for (int c = 0; c < 32; ++c) acc += uu[c] * (double)src[(size_t)c*N_];
  part[(size_t)cc*32768 + pix] = acc;
}

// ---------------- sal reduce -> heat + mask counts ----------------
__global__ __launch_bounds__(256) void k_sal_red(const double* __restrict__ part,
                                                 const double* __restrict__ u,
                                                 float* __restrict__ heat,
                                                 int* __restrict__ counts){
  int pix = blockIdx.x*256 + threadIdx.x;
  int b = pix >> 12;
  double acc = u[512];
  #pragma unroll
  for (int cc = 0; cc < 16; cc++) acc += part[(size_t)cc*32768 + pix];
  float hf = (float)(1.0 / (1.0 + exp(-acc)));
  heat[pix] = hf;
  unsigned long long mfg = __ballot(hf >= 0.5f);
  unsigned long long mbg = __ballot(hf < 0.5f);
  if ((threadIdx.x & 63) == 0){
    atomicAdd(&counts[b*2+0], (int)__popcll(mfg));
    atomicAdd(&counts[b*2+1], (int)__popcll(mbg));
  }
}

// ---------------- bf16 MFMA GEMM:  out[M,N] = A[M,K] @ W[N,K]^T + bias ----------------
// 2-phase double-buffered; LDS 16B-unit XOR swizzle (rule #21).
// EPI 0: f32 out;  EPI 1: relu + bf16;  EPI 2: bf16;  EPI 3: bf16 transposed (vvT)
template<int EPI>
__global__ __launch_bounds__(256) void k_gemm_bt(
    const unsigned short* __restrict__ A, const unsigned short* __restrict__ W,
    const float* __restrict__ bias, void* __restrict__ out,
    int M, int N, int K){
  __shared__ unsigned short smem[2][2][128*64];   // [dbuf][A/B][tile] = 64KB
  int tid = threadIdx.x;
  int w = tid >> 6, l = tid & 63;
  int m0 = blockIdx.x * 128, n0 = blockIdx.y * 128;
  int wr = w >> 1, wc = w & 1;
  int lr = l & 15, lk = l >> 4;
  f32x4 acc[4][4] = {};
  int nt = K >> 6;
  #pragma unroll
  for (int i = 0; i < 4; i++){
    int idx = i*256 + tid;
    int row = idx >> 3, su = ((idx & 7) ^ (row & 7))*8;
    gload_lds16(A + (size_t)(m0+row)*K + su, &smem[0][0][idx*8]);
    gload_lds16(W + (size_t)(n0+row)*K + su, &smem[0][1][idx*8]);
  }
  __syncthreads();
  for (int t = 0; t < nt; ++t){
    int cur = t & 1;
    if (t + 1 < nt){
      int k0 = (t + 1) << 6;
      #pragma unroll
      for (int i = 0; i < 4; i++){
        int idx = i*256 + tid;
        int row = idx >> 3, su = ((idx & 7) ^ (row & 7))*8;
        gload_lds16(A + (size_t)(m0+row)*K + k0 + su, &smem[cur^1][0][idx*8]);
        gload_lds16(W + (size_t)(n0+row)*K + k0 + su, &smem[cur^1][1][idx*8]);
      }
    }
    const unsigned short* ldsA = smem[cur][0];
    const unsigned short* ldsB = smem[cur][1];
    #pragma unroll
    for (int kk = 0; kk < 2; kk++){
      v8bf af[4], bfr[4];
      #pragma unroll
      for (int f = 0; f < 4; f++){
        int ra = wr*64 + f*16 + lr;
        int rb2 = wc*64 + f*16 + lr;
        int u = kk*4 + lk;
        af[f]  = *(const v8bf*)(&ldsA[ra*64 + ((u ^ (ra&7))<<3)]);
        bfr[f] = *(const v8bf*)(&ldsB[rb2*64 + ((u ^ (rb2&7))<<3)]);
      }
      #pragma unroll
      for (int fi = 0; fi < 4; fi++)
        #pragma unroll
        for (int fj = 0; fj < 4; fj++)
          acc[fi][fj] = __builtin_amdgcn_mfma_f32_16x16x32_bf16(af[fi], bfr[fj], acc[fi][fj], 0, 0, 0);
    }
    __syncthreads();
  }
  if (EPI == 1 || EPI == 2){
    unsigned short* st = &smem[0][0][0];
    #pragma unroll
    for (int fj = 0; fj < 4; fj++){
      int col = wc*64 + fj*16 + lr;
      float bv = bias[n0 + col];
      #pragma unroll
      for (int fi = 0; fi < 4; fi++){
        int rl = wr*64 + fi*16 + lk*4;
        #pragma unroll
        for (int r = 0; r < 4; r++){
          float v = acc[fi][fj][r] + bv;
          if (EPI == 1) v = fmaxf(v, 0.f);
          st[(rl + r)*136 + col] = f2b(v);
        }
      }
    }
    __syncthreads();
    #pragma unroll
    for (int it = 0; it < 8; it++){
      int idx = it*256 + tid;
      int row = idx >> 4, c8 = (idx & 15)*8;
      *(uint4*)((unsigned short*)out + (size_t)(m0+row)*N + n0 + c8)
          = *(const uint4*)&st[row*136 + c8];
    }
  } else {
    #pragma unroll
    for (int fj = 0; fj < 4; fj++){
      int col = n0 + wc*64 + fj*16 + lr;
      float bv = bias[col];
      #pragma unroll
      for (int fi = 0; fi < 4; fi++){
        int rb = m0 + wr*64 + fi*16 + lk*4;
        #pragma unroll
        for (int r = 0; r < 4; r++){
          float v = acc[fi][fj][r] + bv;
          if (EPI == 3){
            int row = rb + r;
            ((unsigned short*)out)[((size_t)(row>>6)*256 + col)*64 + (row&63)] = f2b(v);
          } else {
            ((float*)out)[(size_t)(rb + r)*N + col] = v;
          }
        }
      }
    }
  }
}

// ---------------- fused FFN v2: out = relu(A@W1^T+b1)@W2^T + b2 ----------------
// 512 threads (8 waves = 2/SIMD). A [128][256] persistent; 16 F-chunks of 64.
// Cross-phase prefetch: W1(cc+1) issued after sync_a (flies under phase B);
// W2(cc+1) issued after sync_b (flies under phase A of cc+1). 2 syncs/chunk.
// Same 16x16x32 fragments + 16B-unit XOR swizzle as k_gemm_bt; identical math.
__global__ __launch_bounds__(512) void k_ffn(
    const unsigned short* __restrict__ qb, const unsigned short* __restrict__ W1g,
    const float* __restrict__ b1g, const unsigned short* __restrict__ W2g,
    const float* __restrict__ b2g, unsigned short* __restrict__ outb){
  __shared__ unsigned short smem[73728];  // 144 KB
  unsigned short* sA  = smem;             // [128][256] 64KB
  unsigned short* sW1 = smem + 32768;     // [64][256]  32KB
  unsigned short* sW2 = smem + 49152;     // [256][64]  32KB
  unsigned short* sH  = smem + 65536;     // [128][64]  16KB
  int tid = threadIdx.x;
  int w = tid >> 6, l = tid & 63;
  int m0 = blockIdx.x * 128;
  int wm = w >> 2;              // M-half (0..1)
  int wf = w & 3;               // F-quarter (phase A) / C-quarter (phase B)
  int lr = l & 15, lk = l >> 4;

  // stage A (once): 128 rows x 32 units
  #pragma unroll
  for (int i = 0; i < 8; i++){
    int idx = i*512 + tid;
    int row = idx >> 5, g = idx & 31;
    int su = (g & 24) | ((g & 7) ^ (row & 7));
    gload_lds16(qb + (size_t)(m0+row)*256 + su*8, &sA[idx*8]);
  }
  // stage W1(0), W2(0)
  #pragma unroll
  for (int i = 0; i < 4; i++){
    int idx = i*512 + tid;
    int row = idx >> 5, g = idx & 31;
    int su = (g & 24) | ((g & 7) ^ (row & 7));
    gload_lds16(W1g + (size_t)row*256 + su*8, &sW1[idx*8]);
  }
  #pragma unroll
  for (int i = 0; i < 4; i++){
    int idx = i*512 + tid;
    int row = idx >> 3, g = idx & 7;
    int su = g ^ (row & 7);
    gload_lds16(W2g + (size_t)row*1024 + su*8, &sW2[idx*8]);
  }
  __syncthreads();

  f32x4 acc[4][4] = {};
  for (int cc = 0; cc < 16; ++cc){
    // ---- phase A: h[128,64] = A @ W1chunk^T ; wave (wm,wf) -> 64x16 ----
    f32x4 hacc[4] = {};
    #pragma unroll
    for (int ks = 0; ks < 8; ks++){
      int g = ks*4 + lk;
      int rf = wf*16 + lr;
      v8bf bf1 = *(const v8bf*)&sW1[rf*256 + (((g & 24) | ((g & 7) ^ (rf & 7)))<<3)];
      #pragma unroll
      for (int f = 0; f < 4; f++){
        int ra = wm*64 + f*16 + lr;
        v8bf af = *(const v8bf*)&sA[ra*256 + (((g & 24) | ((g & 7) ^ (ra & 7)))<<3)];
        hacc[f] = __builtin_amdgcn_mfma_f32_16x16x32_bf16(af, bf1, hacc[f], 0, 0, 0);
      }
    }
    {
      int fc = wf*16 + lr;
      float b1v = b1g[cc*64 + fc];
      #pragma unroll
      for (int fi = 0; fi < 4; fi++){
        int mr0 = wm*64 + fi*16 + lk*4;
        #pragma unroll
        for (int r = 0; r < 4; r++){
          float v = fmaxf(hacc[fi][r] + b1v, 0.f);
          int mr = mr0 + r;
          sH[mr*64 + (((fc >> 3) ^ (mr & 7))<<3) + (fc & 7)] = f2b(v);
        }
      }
    }
    __syncthreads();   // sync_a: drains W2(cc) prefetch; all waves past phase A
    // prefetch W1(cc+1) -> flies under phase B
    if (cc + 1 < 16){
      int f0n = (cc+1)*64;
      #pragma unroll
      for (int i = 0; i < 4; i++){
        int idx = i*512 + tid;
        int row = idx >> 5, g = idx & 31;
        int su = (g & 24) | ((g & 7) ^ (row & 7));
        gload_lds16(W1g + (size_t)(f0n+row)*256 + su*8, &sW1[idx*8]);
      }
    }
    // ---- phase B: out += h @ W2chunk^T ; wave (wm,wf) -> 64x64 ----
    #pragma unroll
    for (int ks2 = 0; ks2 < 2; ks2++){
      int g = ks2*4 + lk;
      v8bf ha[4], wb[4];
      #pragma unroll
      for (int f = 0; f < 4; f++){
        int rh = wm*64 + f*16 + lr;
        ha[f] = *(const v8bf*)&sH[rh*64 + ((g ^ (rh & 7))<<3)];
      }
      #pragma unroll
      for (int f = 0; f < 4; f++){
        int rc = wf*64 + f*16 + lr;
        wb[f] = *(const v8bf*)&sW2[rc*64 + ((g ^ (rc & 7))<<3)];
      }
      #pragma unroll
      for (int fi = 0; fi < 4; fi++)
        #pragma unroll
        for (int fc = 0; fc < 4; fc++)
          acc[fi][fc] = __builtin_amdgcn_mfma_f32_16x16x32_bf16(ha[fi], wb[fc], acc[fi][fc], 0, 0, 0);
    }
    __syncthreads();   // sync_b: drains W1(cc+1); all waves past phase B
    // prefetch W2(cc+1) -> flies under phase A of cc+1
    if (cc + 1 < 16){
      int f0n = (cc+1)*64;
      #pragma unroll
      for (int i = 0; i < 4; i++){
        int idx = i*512 + tid;
        int row = idx >> 3, g = idx & 7;
        int su = g ^ (row & 7);
        gload_lds16(W2g + (size_t)row*1024 + f0n + su*8, &sW2[idx*8]);
      }
    }
  }
  // epilogue: bias, stage to LDS (pitch 264), coalesced uint4 stores
  unsigned short* st = smem;
  #pragma unroll
  for (int fc = 0; fc < 4; fc++){
    int col = wf*64 + fc*16 + lr;
    float bv = b2g[col];
    #pragma unroll
    for (int fi = 0; fi < 4; fi++){
      int rl = wm*64 + fi*16 + lk*4;
      #pragma unroll
      for (int r = 0; r < 4; r++)
        st[(rl + r)*264 + col] = f2b(acc[fi][fc][r] + bv);
    }
  }
  __syncthreads();
  #pragma unroll
  for (int it = 0; it < 8; it++){
    int idx = it*512 + tid;               // 128 rows x 32 units
    int row = idx >> 5, c8 = (idx & 31)*8;
    *(uint4*)(outb + (size_t)(m0+row)*256 + c8) = *(const uint4*)&st[row*264 + c8];
  }
}

// ---------------- swh[b][side][k][n] = (g*hm + sb)*hm  (bf16) ----------------
__global__ __launch_bounds__(256) void k_swh(const float* __restrict__ g_all,
                                             const float* __restrict__ heat,
                                             const float* __restrict__ soft_b,
                                             unsigned short* __restrict__ swh){
  __shared__ float gl[64*129];
  __shared__ float hml[64];
  int tid = threadIdx.x;
  int blk = blockIdx.x;
  size_t m0 = (size_t)blk*64;
  int b = (int)(m0 >> 12), n0 = (int)(m0 & 4095);
  #pragma unroll
  for (int i = 0; i < 32; i++){
    int idx = i*256 + tid;
    int row = idx >> 7, col = idx & 127;
    gl[row*129 + col] = g_all[(m0 + row)*128 + col];
  }
  if (tid < 64) hml[tid] = heat[(size_t)b*4096 + n0 + tid];
  __syncthreads();
  int k = tid >> 2, j0 = (tid & 3)*16;
  #pragma unroll
  for (int s = 0; s < 2; s++){
    float sb = soft_b[s*64 + k];
    unsigned short vals[16];
    #pragma unroll
    for (int j = 0; j < 16; j++){
      int n = j0 + j;
      float h = hml[n];
      float hm = s ? (1.0f - h) : h;
      vals[j] = f2b((gl[n*129 + s*64 + k]*hm + sb)*hm);
    }
    unsigned short* dst = swh + (((size_t)b*2 + s)*64 + k)*4096 + n0 + j0;
    uint4 o0, o1;
    o0.x = vals[0] | ((uint32_t)vals[1]<<16);  o0.y = vals[2] | ((uint32_t)vals[3]<<16);
    o0.z = vals[4] | ((uint32_t)vals[5]<<16);  o0.w = vals[6] | ((uint32_t)vals[7]<<16);
    o1.x = vals[8] | ((uint32_t)vals[9]<<16);  o1.y = vals[10]| ((uint32_t)vals[11]<<16);
    o1.z = vals[12]| ((uint32_t)vals[13]<<16); o1.w = vals[14]| ((uint32_t)vals[15]<<16);
    *(uint4*)dst = o0;
    *(uint4*)(dst + 8) = o1;
  }
}

// ---------------- pool GEMM (split-K): pp[kc][b][128][256] = swh[b] @ featC[b]^T ----------------
__global__ __launch_bounds__(256) void k_poolgemm(
    const unsigned short* __restrict__ swh, const unsigned short* __restrict__ featC,
    float* __restrict__ pp){
  __shared__ unsigned short ldsA[128*64];
  __shared__ unsigned short ldsB[128*64];
  int tid = threadIdx.x;
  int w = tid >> 6, l = tid & 63;
  int kc = blockIdx.x, nt = blockIdx.y, b = blockIdx.z;
  int wr = w >> 1, wc = w & 1;
  int lr = l & 15, lk = l >> 4;
  const unsigned short* A = swh  + (size_t)b*128*4096 + kc*512;
  const unsigned short* W = featC + ((size_t)b*256 + nt*128)*4096 + kc*512;
  f32x4 acc[4][4] = {};
  for (int k0 = 0; k0 < 512; k0 += 64){
    #pragma unroll
    for (int i = 0; i < 4; i++){
      int idx = i*256 + tid;
      int row = idx >> 3, su = (idx & 7) ^ (row & 7);
      gload_lds16(A + (size_t)row*4096 + k0 + su*8, &ldsA[idx*8]);
    }
    #pragma unroll
    for (int i = 0; i < 4; i++){
      int idx = i*256 + tid;
      int row = idx >> 3, su = (idx & 7) ^ (row & 7);
      gload_lds16(W + (size_t)row*4096 + k0 + su*8, &ldsB[idx*8]);
    }
    __syncthreads();
    #pragma unroll
    for (int kk = 0; kk < 2; kk++){
      v8bf af[4], bfr[4];
      #pragma unroll
      for (int f = 0; f < 4; f++){
        int ra = wr*64 + f*16 + lr;
        int rb2 = wc*64 + f*16 + lr;
        int u = kk*4 + lk;
        af[f]  = *(const v8bf*)(&ldsA[ra*64 + ((u ^ (ra&7))<<3)]);
        bfr[f] = *(const v8bf*)(&ldsB[rb2*64 + ((u ^ (rb2&7))<<3)]);
      }
      #pragma unroll
      for (int fi = 0; fi < 4; fi++)
        #pragma unroll
        for (int fj = 0; fj < 4; fj++)
          acc[fi][fj] = __builtin_amdgcn_mfma_f32_16x16x32_bf16(af[fi], bfr[fj], acc[fi][fj], 0, 0, 0);
    }
    __syncthreads();
  }
  float* dst = pp + ((size_t)kc*8 + b)*128*256;
  #pragma unroll
  for (int fj = 0; fj < 4; fj++){
    int col = nt*128 + wc*64 + fj*16 + lr;
    #pragma unroll
    for (int fi = 0; fi < 4; fi++){
      int rb = wr*64 + fi*16 + lk*4;
      #pragma unroll
      for (int r = 0; r < 4; r++)
        dst[(size_t)(rb + r)*256 + col] = acc[fi][fj][r];
    }
  }
}

// ---------------- reduce split-K partials -> pool_bf_s[side][b*64+k][c] bf16 ----------------
__global__ __launch_bounds__(256) void k_pool2b(const float* __restrict__ pp,
                                                unsigned short* __restrict__ pool_bf_s){
  int bk = blockIdx.x, side = blockIdx.y, c = threadIdx.x;
  int b = bk >> 6, k = bk & 63;
  float s = 0.f;
  #pragma unroll
  for (int kc = 0; kc < 8; kc++)
    s += pp[(((size_t)kc*8 + b)*128 + side*64 + k)*256 + c];
  pool_bf_s[((size_t)side*512 + bk)*256 + c] = f2b(s);
}

// ---------------- MFMA attention: 64 q-rows/block, 8 heads, 64 keys, DH=32 ----------------
__global__ __launch_bounds__(256) void k_attn2(
    const unsigned short* __restrict__ qq, const unsigned short* __restrict__ kk,
    const unsigned short* __restrict__ vvT, unsigned short* __restrict__ obf){
  __shared__ unsigned short sk[64*256];
  __shared__ unsigned short svT[256*64];
  __shared__ unsigned short sp[4][16*64];
  __shared__ unsigned short sow[4][16*32];
  int tid = threadIdx.x, w = tid >> 6, l = tid & 63;
  int blk = blockIdx.x, b = blk >> 6;
  int l15 = l & 15, lg = l >> 4;
  const uint4* ksrc = (const uint4*)(kk + (size_t)b*64*256);
  #pragma unroll
  for (int i = 0; i < 8; i++){
    int u = i*256 + tid;
    int row = u >> 5, j = u & 31;
    *(uint4*)&sk[row*256 + ((j ^ (row&7))<<3)] = ksrc[u];
  }
  const uint4* vsrc = (const uint4*)(vvT + (size_t)b*256*64);
  #pragma unroll
  for (int i = 0; i < 8; i++){
    int u = i*256 + tid;
    int row = u >> 3, j = u & 7;
    *(uint4*)&svT[row*64 + ((j ^ (row&7))<<3)] = vsrc[u];
  }
  __syncthreads();
  size_t qrow = (size_t)blk*64 + w*16 + l15;
  for (int h = 0; h < 8; h++){
    v8bf aq = *(const v8bf*)(qq + qrow*256 + h*32 + lg*8);
    f32x4 s[4];
    #pragma unroll
    for (int kt = 0; kt < 4; kt++){
      int row = kt*16 + l15;
      v8bf bk = *(const v8bf*)&sk[row*256 + (((h*4 + lg) ^ (row&7))<<3)];
      f32x4 z = {};
      s[kt] = __builtin_amdgcn_mfma_f32_16x16x32_bf16(aq, bk, z, 0, 0, 0);
    }
    #pragma unroll
    for (int r = 0; r < 4; r++){
      float v0 = s[0][r]*SCALE_, v1 = s[1][r]*SCALE_;
      float v2 = s[2][r]*SCALE_, v3 = s[3][r]*SCALE_;
      float mx = fmaxf(fmaxf(v0, v1), fmaxf(v2, v3));
      mx = fmaxf(mx, __shfl_xor(mx, 1));
      mx = fmaxf(mx, __shfl_xor(mx, 2));
      mx = fmaxf(mx, __shfl_xor(mx, 4));
      mx = fmaxf(mx, __shfl_xor(mx, 8));
      float e0 = __expf(v0-mx), e1 = __expf(v1-mx);
      float e2 = __expf(v2-mx), e3 = __expf(v3-mx);
      float sum = e0+e1+e2+e3;
      sum += __shfl_xor(sum, 1); sum += __shfl_xor(sum, 2);
      sum += __shfl_xor(sum, 4); sum += __shfl_xor(sum, 8);
      float inv = 1.0f/sum;
      s[0][r] = e0*inv; s[1][r] = e1*inv; s[2][r] = e2*inv; s[3][r] = e3*inv;
    }
    #pragma unroll
    for (int kt = 0; kt < 4; kt++){
      int colu = kt*2 + (l15>>3);
      #pragma unroll
      for (int r = 0; r < 4; r++){
        int row = lg*4 + r;
        sp[w][row*64 + ((colu ^ (row&7))<<3) + (l&7)] = f2b(s[kt][r]);
      }
    }
    f32x4 o[2] = {};
    #pragma unroll
    for (int k2 = 0; k2 < 2; k2++){
      v8bf pa = *(const v8bf*)&sp[w][l15*64 + (((k2*4 + lg) ^ (l15&7))<<3)];
      #pragma unroll
      for (int dt = 0; dt < 2; dt++){
        int vrow = h*32 + dt*16 + l15;
        v8bf bv = *(const v8bf*)&svT[vrow*64 + (((k2*4 + lg) ^ (vrow&7))<<3)];
        o[dt] = __builtin_amdgcn_mfma_f32_16x16x32_bf16(pa, bv, o[dt], 0, 0, 0);
      }
    }
    #pragma unroll
    for (int dt = 0; dt < 2; dt++)
      #pragma unroll
      for (int r = 0; r < 4; r++)
        sow[w][(lg*4 + r)*32 + dt*16 + l15] = f2b(o[dt][r]);
    uint4 ov = *(const uint4*)&sow[w][l15*32 + lg*8];
    *(uint4*)(obf + qrow*256 + h*32 + lg*8) = ov;
  }
}

// ---------------- residual(bf16 or f32) + bf16 delta -> LayerNorm -> bf16 ----------------
template<int RF32>
__global__ __launch_bounds__(256) void k_ln2(
    const void* __restrict__ resid, const unsigned short* __restrict__ delta,
    const float* __restrict__ g, const float* __restrict__ bta,
    unsigned short* __restrict__ qout){
  int wv = threadIdx.x >> 6, l = threadIdx.x & 63;
  size_t m = (size_t)blockIdx.x*4 + wv;
  uint2 dv = *(const uint2*)(delta + m*256 + l*4);
  float d0 = b2f((unsigned short)(dv.x & 0xffff)), d1 = b2f((unsigned short)(dv.x >> 16));
  float d2 = b2f((unsigned short)(dv.y & 0xffff)), d3 = b2f((unsigned short)(dv.y >> 16));
  float x0, x1, x2, x3;
  if (RF32){
    float4 rv = *(const float4*)((const float*)resid + m*256 + l*4);
    x0 = rv.x+d0; x1 = rv.y+d1; x2 = rv.z+d2; x3 = rv.w+d3;
  } else {
    uint2 rv = *(const uint2*)((const unsigned short*)resid + m*256 + l*4);
    x0 = b2f((unsigned short)(rv.x & 0xffff)) + d0;
    x1 = b2f((unsigned short)(rv.x >> 16)) + d1;
    x2 = b2f((unsigned short)(rv.y & 0xffff)) + d2;
    x3 = b2f((unsigned short)(rv.y >> 16)) + d3;
  }
  float s = x0+x1+x2+x3;
  float ss = x0*x0+x1*x1+x2*x2+x3*x3;
  #pragma unroll
  for (int off = 32; off; off >>= 1){
    s  += __shfl_xor(s, off);
    ss += __shfl_xor(ss, off);
  }
  float mean = s * (1.0f/256.0f);
  float var = ss * (1.0f/256.0f) - mean*mean;
  float rstd = 1.0f / sqrtf(var + 1e-5f);
  float4 gv = *(const float4*)(g + l*4);
  float4 bv = *(const float4*)(bta + l*4);
  float y0 = (x0-mean)*rstd*gv.x + bv.x;
  float y1 = (x1-mean)*rstd*gv.y + bv.y;
  float y2 = (x2-mean)*rstd*gv.z + bv.z;
  float y3 = (x3-mean)*rstd*gv.w + bv.w;
  uint32_t p0 = (uint32_t)f2b(y0) | ((uint32_t)f2b(y1)<<16);
  uint32_t p1 = (uint32_t)f2b(y2) | ((uint32_t)f2b(y3)<<16);
  *(uint2*)(qout + m*256 + l*4) = make_uint2(p0,p1);
}

// ---------------- final select + transpose [B,N,C] -> [B,C,N] ----------------
__global__ __launch_bounds__(256) void k_select(
    const unsigned short* __restrict__ qA, const unsigned short* __restrict__ qB,
    const float* __restrict__ featT, const float* __restrict__ heat,
    const int* __restrict__ counts, float* __restrict__ out){
  __shared__ float t[32][33];
  int b = blockIdx.z;
  int n0 = blockIdx.x*32, c0 = blockIdx.y*32;
  int tx = threadIdx.x, ty = threadIdx.y;
  bool valid = (counts[b*2] > 0) && (counts[b*2+1] > 0);
  #pragma unroll
  for (int i = 0; i < 4; i++){
    int nl = ty*4+i;
    size_t m = (size_t)b*4096 + n0 + nl;
    float v;
    if (!valid) v = featT[m*256 + c0 + tx];
    else {
      bool fg = heat[(size_t)b*4096 + n0 + nl] >= 0.5f;
      v = fg ? b2f(qA[m*256 + c0 + tx]) : b2f(qB[m*256 + c0 + tx]);
    }
    t[nl][tx] = v;
  }
  __syncthreads();
  #pragma unroll
  for (int i = 0; i < 4; i++){
    int cl = ty*4+i;
    out[((size_t)b*256 + c0 + cl)*4096 + n0 + tx] = t[tx][cl];
  }
}

extern "C" void kernel_launch(void* const* d_in, const int* in_sizes, int n_in,
                              void* d_out, int out_size, void* d_ws, size_t ws_size,
                              hipStream_t stream){
  const float* x         = (const float*)d_in[0];
  const float* y         = (const float*)d_in[1];
  const float* proj_w    = (const float*)d_in[2];
  const float* proj_b    = (const float*)d_in[3];
  const float* sal_w     = (const float*)d_in[4];
  const float* sal_b     = (const float*)d_in[5];
  const float* soft_w    = (const float*)d_in[6];
  const float* soft_b    = (const float*)d_in[7];
  const float* attn_in_w = (const float*)d_in[8];
  const float* attn_in_b = (const float*)d_in[9];
  const float* attn_out_w= (const float*)d_in[10];
  const float* attn_out_b= (const float*)d_in[11];
  const float* n1_g      = (const float*)d_in[12];
  const float* n1_b      = (const float*)d_in[13];
  const float* ffn_w1    = (const float*)d_in[14];
  const float* ffn_b1    = (const float*)d_in[15];
  const float* ffn_w2    = (const float*)d_in[16];
  const float* ffn_b2    = (const float*)d_in[17];
  const float* n2_g      = (const float*)d_in[18];
  const float* n2_b      = (const float*)d_in[19];
  float* out = (float*)d_out;

  // ---- workspace layout (~204 MB; proven limit is >= 263 MB) ----
  char* p = (char*)d_ws;
  auto alloc = [&](size_t bytes){ char* r = p; p += (bytes + 255) & ~(size_t)255; return r; };
  unsigned short* hbf   = (unsigned short*)alloc((size_t)M_*FF_*2);
  unsigned short* xcT   = hbf;            // [M,512] bf16, dead before layers
  unsigned short* qq_bf = hbf;            // [M,C] bf16, consumed by attn
  float* featT = (float*)alloc((size_t)M_*C_*4);
  unsigned short* qAb = (unsigned short*)alloc((size_t)M_*C_*2);
  unsigned short* swh = qAb;              // dead before side-0 n1
  unsigned short* qBb = (unsigned short*)alloc((size_t)M_*C_*2);
  unsigned short* obf = (unsigned short*)alloc((size_t)M_*C_*2);
  unsigned short* featC = obf;            // dead before first attn
  unsigned short* featbf = (unsigned short*)alloc((size_t)M_*C_*2);
  unsigned short* tmpb = (unsigned short*)alloc((size_t)M_*C_*2);
  float* g_all = (float*)tmpb;            // dead before layers
  float* pp    = (float*)alloc((size_t)8*8*128*256*4);   // 8.4MB; also hosts sal partials early
  double* salp = (double*)pp;             // 4MB, dead before poolgemm
  unsigned short* pool_bf_s = (unsigned short*)alloc((size_t)2*512*256*2);
  unsigned short* kk_bf = (unsigned short*)alloc((size_t)B_*K_*C_*2);
  unsigned short* vvT_bf= (unsigned short*)alloc((size_t)B_*C_*K_*2);
  float* heat = (float*)alloc((size_t)B_*N_*4);
  double* u   = (double*)alloc(513*8);
  int* counts = (int*)alloc(64);
  float* zbias = (float*)alloc(512);
  unsigned short* projw_bf = (unsigned short*)alloc((size_t)C_*512*2);
  unsigned short* aiw_bf = (unsigned short*)alloc((size_t)2*L_*768*C_*2);
  unsigned short* aow_bf = (unsigned short*)alloc((size_t)2*L_*C_*C_*2);
  unsigned short* f1w_bf = (unsigned short*)alloc((size_t)2*L_*FF_*C_*2);
  unsigned short* f2w_bf = (unsigned short*)alloc((size_t)2*L_*C_*FF_*2);
  unsigned short* sw2_bf = (unsigned short*)alloc((size_t)2*K_*C_*2);

  hipMemsetAsync(counts, 0, 64, stream);
  hipMemsetAsync(zbias, 0, 512, stream);
  k_compute_u<<<1, 512, 0, stream>>>(sal_w, proj_w, proj_b, sal_b, u);
  k_sal_part<<<dim3(128, 16), 256, 0, stream>>>(x, y, u, salp);
  k_sal_red<<<128, 256, 0, stream>>>(salp, u, heat, counts);

  auto conv = [&](const float* s, unsigned short* d, size_t n){
    k_f32_to_bf16<<<(unsigned)((n/4 + 255)/256), 256, 0, stream>>>(s, d, (int)n);
  };
  conv(proj_w,     projw_bf, (size_t)C_*512);
  conv(attn_in_w,  aiw_bf,   (size_t)2*L_*768*C_);
  conv(attn_out_w, aow_bf,   (size_t)2*L_*C_*C_);
  conv(ffn_w1,     f1w_bf,   (size_t)2*L_*FF_*C_);
  conv(ffn_w2,     f2w_bf,   (size_t)2*L_*C_*FF_);
  conv(soft_w,     sw2_bf,   (size_t)2*K_*C_);

  k_build_xcT<<<dim3(N_/32, 512/32, B_), dim3(32,8), 0, stream>>>(x, y, xcT);
  k_gemm_bt<0><<<dim3(M_/128, C_/128), 256, 0, stream>>>(xcT, projw_bf, proj_b, featT, M_, C_, 512);
  k_featmir<<<dim3(N_/32, C_/32, B_), dim3(32,8), 0, stream>>>(featT, featbf, featC);

  // sw/pool pipeline (both sides at once)
  k_gemm_bt<0><<<dim3(M_/128, 1), 256, 0, stream>>>(featbf, sw2_bf, zbias, g_all, M_, 128, C_);
  k_swh<<<M_/64, 256, 0, stream>>>(g_all, heat, soft_b, swh);
  k_poolgemm<<<dim3(8, 2, B_), 256, 0, stream>>>(swh, featC, pp);
  k_pool2b<<<dim3(512, 2), 256, 0, stream>>>(pp, pool_bf_s);

  for (int side = 0; side < 2; ++side){
    unsigned short* qb = side ? qBb : qAb;
    const unsigned short* poolS = pool_bf_s + (size_t)side*512*256;
    for (int lyr = 0; lyr < L_; ++lyr){
      int sl = side*L_ + lyr;
      const unsigned short* iw = aiw_bf + (size_t)sl*768*C_;
      const float* ib = attn_in_b + (size_t)sl*768;
      const unsigned short* qin = (lyr == 0) ? featbf : qb;
      k_gemm_bt<2><<<dim3(M_/128, C_/128), 256, 0, stream>>>(qin, iw, ib, qq_bf, M_, C_, C_);
      k_gemm_bt<2><<<dim3((B_*K_)/128, C_/128), 256, 0, stream>>>(poolS, iw + 256*C_, ib + 256, kk_bf, B_*K_, C_, C_);
      k_gemm_bt<3><<<dim3((B_*K_)/128, C_/128), 256, 0, stream>>>(poolS, iw + 512*C_, ib + 512, vvT_bf, B_*K_, C_, C_);
      k_attn2<<<M_/64, 256, 0, stream>>>(qq_bf, kk_bf, vvT_bf, obf);
      k_gemm_bt<2><<<dim3(M_/128, C_/128), 256, 0, stream>>>(obf, aow_bf + (size_t)sl*C_*C_, attn_out_b + (size_t)sl*C_, tmpb, M_, C_, C_);
      if (lyr == 0)
        k_ln2<1><<<M_/4, 256, 0, stream>>>(featT, tmpb, n1_g + (size_t)sl*C_, n1_b + (size_t)sl*C_, qb);
      else
        k_ln2<0><<<M_/4, 256, 0, stream>>>(qb, tmpb, n1_g + (size_t)sl*C_, n1_b + (size_t)sl*C_, qb);
      k_ffn<<<M_/128, 512, 0, stream>>>(qb, f1w_bf + (size_t)sl*FF_*C_, ffn_b1 + (size_t)sl*FF_,
                                        f2w_bf + (size_t)sl*C_*FF_, ffn_b2 + (size_t)sl*C_, tmpb);
      k_ln2<0><<<M_/4, 256, 0, stream>>>(qb, tmpb, n2_g + (size_t)sl*C_, n2_b + (size_t)sl*C_, qb);
    }
  }
  k_select<<<dim3(N_/32, C_/32, B_), dim3(32,8), 0, stream>>>(qAb, qBb, featT, heat, counts, out);
}

// Round 9
// 822.598 us; speedup vs baseline: 1.1800x; 1.0398x over previous
//
#include <hip/hip_runtime.h>
#include <stdint.h>

#define B_ 8
#define C_ 256
#define N_ 4096
#define K_ 64
#define NH_ 8
#define FF_ 1024
#define L_ 3
#define M_ (B_*N_)
#define SCALE_ 0.17677669529663687f

typedef float f32x4 __attribute__((ext_vector_type(4)));
typedef __bf16 v8bf __attribute__((ext_vector_type(8)));

__device__ __forceinline__ float b2f(unsigned short h){
  union { uint32_t u; float f; } v; v.u = ((uint32_t)h) << 16; return v.f;
}
__device__ __forceinline__ unsigned short f2b(float f){
  union { float f; uint32_t u; } v; v.f = f;
  uint32_t r = v.u + 0x7fffu + ((v.u >> 16) & 1u);
  return (unsigned short)(r >> 16);
}
__device__ __forceinline__ void gload_lds16(const void* g, void* l){
  __builtin_amdgcn_global_load_lds(
      (const __attribute__((address_space(1))) unsigned int*)g,
      (__attribute__((address_space(3))) unsigned int*)l, 16, 0, 0);
}

// ---------------- fp32 -> bf16 convert ----------------
__global__ __launch_bounds__(256) void k_f32_to_bf16(const float* __restrict__ src,
                                                     unsigned short* __restrict__ dst, int n){
  int i4 = (blockIdx.x*256 + threadIdx.x)*4;
  if (i4 >= n) return;
  float4 v = *(const float4*)(src + i4);
  uint32_t p0 = (uint32_t)f2b(v.x) | ((uint32_t)f2b(v.y) << 16);
  uint32_t p1 = (uint32_t)f2b(v.z) | ((uint32_t)f2b(v.w) << 16);
  *(uint2*)(dst + i4) = make_uint2(p0, p1);
}

// ---------------- build xcT: [B,N,512] bf16 from x,y [B,256,N] f32 ----------------
__global__ __launch_bounds__(256) void k_build_xcT(const float* __restrict__ x,
                                                   const float* __restrict__ y,
                                                   unsigned short* __restrict__ xcT){
  __shared__ float t[32][33];
  int b = blockIdx.z;
  int n0 = blockIdx.x*32, c0 = blockIdx.y*32;
  int tx = threadIdx.x, ty = threadIdx.y;
  const float* src = (c0 < 256) ? (x + ((size_t)b*256 + c0)*N_)
                                : (y + ((size_t)b*256 + (c0-256))*N_);
  #pragma unroll
  for (int i = 0; i < 4; i++){
    int cl = ty*4 + i;
    t[cl][tx] = src[(size_t)cl*N_ + n0 + tx];
  }
  __syncthreads();
  #pragma unroll
  for (int i = 0; i < 4; i++){
    int nl = ty*4 + i;
    xcT[((size_t)b*N_ + n0 + nl)*512 + c0 + tx] = f2b(t[tx][nl]);
  }
}

// ---------------- feat mirrors ----------------
__global__ __launch_bounds__(256) void k_featmir(const float* __restrict__ featT,
                                                 unsigned short* __restrict__ featbf,
                                                 unsigned short* __restrict__ featC){
  __shared__ float t[32][33];
  int b = blockIdx.z;
  int n0 = blockIdx.x*32, c0 = blockIdx.y*32;
  int tx = threadIdx.x, ty = threadIdx.y;
  #pragma unroll
  for (int i = 0; i < 4; i++){
    int nl = ty*4 + i;
    size_t m = (size_t)b*N_ + n0 + nl;
    float v = featT[m*256 + c0 + tx];
    t[nl][tx] = v;
    featbf[m*256 + c0 + tx] = f2b(v);
  }
  __syncthreads();
  #pragma unroll
  for (int i = 0; i < 4; i++){
    int cl = ty*4 + i;
    featC[((size_t)b*256 + c0 + cl)*(size_t)N_ + n0 + tx] = f2b(t[tx][cl]);
  }
}

// ---------------- combined saliency vector (fp64) ----------------
__global__ __launch_bounds__(512) void k_compute_u(const float* __restrict__ sal_w,
                                                   const float* __restrict__ proj_w,
                                                   const float* __restrict__ proj_b,
                                                   const float* __restrict__ sal_b,
                                                   double* __restrict__ u){
  int c2 = threadIdx.x;
  double acc = 0.0;
  for (int c = 0; c < 256; ++c)
    acc += (double)sal_w[c] * (double)proj_w[(size_t)c*512 + c2];
  u[c2] = acc;
  if (c2 == 0){
    double s0 = (double)sal_b[0];
    for (int c = 0; c < 256; ++c) s0 += (double)sal_w[c] * (double)proj_b[c];
    u[512] = s0;
  }
}

// ---------------- sal partials ----------------
__global__ __launch_bounds__(256) void k_sal_part(const float* __restrict__ x,
                                                  const float* __restrict__ y,
                                                  const double* __restrict__ u,
                                                  double* __restrict__ part){
  int pix = blockIdx.x*256 + threadIdx.x;
  int cc = blockIdx.y;
  int b = pix >> 12, n = pix & 4095;
  int c0 = cc*32;
  const float* src = (c0 < 256) ? (x + ((size_t)b*256 + c0)*N_ + n)
                                : (y + ((size_t)b*256 + (c0-256))*N_ + n);
  const double* uu = u + c0;
  double acc = 0.0;
  #pragma unroll 8
  for (int c = 0; c < 32; ++c) acc += uu[c] * (double)src[(size_t)c*N_];
  part[(size_t)cc*32768 + pix] = acc;
}

// ---------------- sal reduce -> heat + mask counts ----------------
__global__ __launch_bounds__(256) void k_sal_red(const double* __restrict__ part,
                                                 const double* __restrict__ u,
                                                 float* __restrict__ heat,
                                                 int* __restrict__ counts){
  int pix = blockIdx.x*256 + threadIdx.x;
  int b = pix >> 12;
  double acc = u[512];
  #pragma unroll
  for (int cc = 0; cc < 16; cc++) acc += part[(size_t)cc*32768 + pix];
  float hf = (float)(1.0 / (1.0 + exp(-acc)));
  heat[pix] = hf;
  unsigned long long mfg = __ballot(hf >= 0.5f);
  unsigned long long mbg = __ballot(hf < 0.5f);
  if ((threadIdx.x & 63) == 0){
    atomicAdd(&counts[b*2+0], (int)__popcll(mfg));
    atomicAdd(&counts[b*2+1], (int)__popcll(mbg));
  }
}

// ---------------- bf16 MFMA GEMM (2-phase dbuf, XOR swizzle) ----------------
template<int EPI>
__global__ __launch_bounds__(256) void k_gemm_bt(
    const unsigned short* __restrict__ A, const unsigned short* __restrict__ W,
    const float* __restrict__ bias, void* __restrict__ out,
    int M, int N, int K){
  __shared__ unsigned short smem[2][2][128*64];
  int tid = threadIdx.x;
  int w = tid >> 6, l = tid & 63;
  int m0 = blockIdx.x * 128, n0 = blockIdx.y * 128;
  int wr = w >> 1, wc = w & 1;
  int lr = l & 15, lk = l >> 4;
  f32x4 acc[4][4] = {};
  int nt = K >> 6;
  #pragma unroll
  for (int i = 0; i < 4; i++){
    int idx = i*256 + tid;
    int row = idx >> 3, su = ((idx & 7) ^ (row & 7))*8;
    gload_lds16(A + (size_t)(m0+row)*K + su, &smem[0][0][idx*8]);
    gload_lds16(W + (size_t)(n0+row)*K + su, &smem[0][1][idx*8]);
  }
  __syncthreads();
  for (int t = 0; t < nt; ++t){
    int cur = t & 1;
    if (t + 1 < nt){
      int k0 = (t + 1) << 6;
      #pragma unroll
      for (int i = 0; i < 4; i++){
        int idx = i*256 + tid;
        int row = idx >> 3, su = ((idx & 7) ^ (row & 7))*8;
        gload_lds16(A + (size_t)(m0+row)*K + k0 + su, &smem[cur^1][0][idx*8]);
        gload_lds16(W + (size_t)(n0+row)*K + k0 + su, &smem[cur^1][1][idx*8]);
      }
    }
    const unsigned short* ldsA = smem[cur][0];
    const unsigned short* ldsB = smem[cur][1];
    #pragma unroll
    for (int kk = 0; kk < 2; kk++){
      v8bf af[4], bfr[4];
      #pragma unroll
      for (int f = 0; f < 4; f++){
        int ra = wr*64 + f*16 + lr;
        int rb2 = wc*64 + f*16 + lr;
        int u = kk*4 + lk;
        af[f]  = *(const v8bf*)(&ldsA[ra*64 + ((u ^ (ra&7))<<3)]);
        bfr[f] = *(const v8bf*)(&ldsB[rb2*64 + ((u ^ (rb2&7))<<3)]);
      }
      #pragma unroll
      for (int fi = 0; fi < 4; fi++)
        #pragma unroll
        for (int fj = 0; fj < 4; fj++)
          acc[fi][fj] = __builtin_amdgcn_mfma_f32_16x16x32_bf16(af[fi], bfr[fj], acc[fi][fj], 0, 0, 0);
    }
    __syncthreads();
  }
  if (EPI == 1 || EPI == 2){
    unsigned short* st = &smem[0][0][0];
    #pragma unroll
    for (int fj = 0; fj < 4; fj++){
      int col = wc*64 + fj*16 + lr;
      float bv = bias[n0 + col];
      #pragma unroll
      for (int fi = 0; fi < 4; fi++){
        int rl = wr*64 + fi*16 + lk*4;
        #pragma unroll
        for (int r = 0; r < 4; r++){
          float v = acc[fi][fj][r] + bv;
          if (EPI == 1) v = fmaxf(v, 0.f);
          st[(rl + r)*136 + col] = f2b(v);
        }
      }
    }
    __syncthreads();
    #pragma unroll
    for (int it = 0; it < 8; it++){
      int idx = it*256 + tid;
      int row = idx >> 4, c8 = (idx & 15)*8;
      *(uint4*)((unsigned short*)out + (size_t)(m0+row)*N + n0 + c8)
          = *(const uint4*)&st[row*136 + c8];
    }
  } else {
    #pragma unroll
    for (int fj = 0; fj < 4; fj++){
      int col = n0 + wc*64 + fj*16 + lr;
      float bv = bias[col];
      #pragma unroll
      for (int fi = 0; fi < 4; fi++){
        int rb = m0 + wr*64 + fi*16 + lk*4;
        #pragma unroll
        for (int r = 0; r < 4; r++){
          float v = acc[fi][fj][r] + bv;
          if (EPI == 3){
            int row = rb + r;
            ((unsigned short*)out)[((size_t)(row>>6)*256 + col)*64 + (row&63)] = f2b(v);
          } else {
            ((float*)out)[(size_t)(rb + r)*N + col] = v;
          }
        }
      }
    }
  }
}

// ---------------- merged K/V projection: M=512, N=256, K=256 ----------------
// blockIdx.z: 0 -> kk_bf (row-major), 1 -> vvT_bf (EPI3 transposed layout)
__global__ __launch_bounds__(256) void k_kv(
    const unsigned short* __restrict__ pool, const unsigned short* __restrict__ iw,
    const float* __restrict__ ib, unsigned short* __restrict__ kk_bf,
    unsigned short* __restrict__ vvT_bf){
  __shared__ unsigned short smem[2][2][128*64];
  int tid = threadIdx.x;
  int w = tid >> 6, l = tid & 63;
  int m0 = blockIdx.x * 128, n0 = blockIdx.y * 128;
  int isv = blockIdx.z;
  const unsigned short* W = iw + (size_t)(isv ? 512 : 256)*256;
  const float* bias = ib + (isv ? 512 : 256);
  int wr = w >> 1, wc = w & 1;
  int lr = l & 15, lk = l >> 4;
  f32x4 acc[4][4] = {};
  #pragma unroll
  for (int i = 0; i < 4; i++){
    int idx = i*256 + tid;
    int row = idx >> 3, su = ((idx & 7) ^ (row & 7))*8;
    gload_lds16(pool + (size_t)(m0+row)*256 + su, &smem[0][0][idx*8]);
    gload_lds16(W + (size_t)(n0+row)*256 + su, &smem[0][1][idx*8]);
  }
  __syncthreads();
  for (int t = 0; t < 4; ++t){
    int cur = t & 1;
    if (t + 1 < 4){
      int k0 = (t + 1) << 6;
      #pragma unroll
      for (int i = 0; i < 4; i++){
        int idx = i*256 + tid;
        int row = idx >> 3, su = ((idx & 7) ^ (row & 7))*8;
        gload_lds16(pool + (size_t)(m0+row)*256 + k0 + su, &smem[cur^1][0][idx*8]);
        gload_lds16(W + (size_t)(n0+row)*256 + k0 + su, &smem[cur^1][1][idx*8]);
      }
    }
    const unsigned short* ldsA = smem[cur][0];
    const unsigned short* ldsB = smem[cur][1];
    #pragma unroll
    for (int kk = 0; kk < 2; kk++){
      v8bf af[4], bfr[4];
      #pragma unroll
      for (int f = 0; f < 4; f++){
        int ra = wr*64 + f*16 + lr;
        int rb2 = wc*64 + f*16 + lr;
        int u = kk*4 + lk;
        af[f]  = *(const v8bf*)(&ldsA[ra*64 + ((u ^ (ra&7))<<3)]);
        bfr[f] = *(const v8bf*)(&ldsB[rb2*64 + ((u ^ (rb2&7))<<3)]);
      }
      #pragma unroll
      for (int fi = 0; fi < 4; fi++)
        #pragma unroll
        for (int fj = 0; fj < 4; fj++)
          acc[fi][fj] = __builtin_amdgcn_mfma_f32_16x16x32_bf16(af[fi], bfr[fj], acc[fi][fj], 0, 0, 0);
    }
    __syncthreads();
  }
  #pragma unroll
  for (int fj = 0; fj < 4; fj++){
    int col = n0 + wc*64 + fj*16 + lr;
    float bv = bias[col];
    #pragma unroll
    for (int fi = 0; fi < 4; fi++){
      int rb = m0 + wr*64 + fi*16 + lk*4;
      #pragma unroll
      for (int r = 0; r < 4; r++){
        float v = acc[fi][fj][r] + bv;
        int row = rb + r;
        if (isv)
          vvT_bf[((size_t)(row>>6)*256 + col)*64 + (row&63)] = f2b(v);
        else
          kk_bf[(size_t)row*256 + col] = f2b(v);
      }
    }
  }
}

// ---------------- fused FFN v3 + LayerNorm2: qout = LN(qb + relu(qb@W1^T+b1)@W2^T + b2) ----------------
// 512 threads (8 waves). A [128][256] persistent in sA (= residual for LN).
// sH key = (mr ^ (mr>>3)) & 7 -> distinct keys for rows {m,m+4,m+8,m+12} (write-conflict fix).
// Cross-phase W prefetch as v2. LN fused in epilogue using f32 delta + sA residual.
__global__ __launch_bounds__(512) void k_ffn(
    const unsigned short* __restrict__ qb, const unsigned short* __restrict__ W1g,
    const float* __restrict__ b1g, const unsigned short* __restrict__ W2g,
    const float* __restrict__ b2g, const float* __restrict__ n2g,
    const float* __restrict__ n2b, unsigned short* __restrict__ qout){
  __shared__ unsigned short smem[73728];  // 144 KB
  unsigned short* sA  = smem;             // [128][256] 64KB
  unsigned short* sW1 = smem + 32768;     // [64][256]  32KB
  unsigned short* sW2 = smem + 49152;     // [256][64]  32KB
  unsigned short* sH  = smem + 65536;     // [128][64]  16KB
  int tid = threadIdx.x;
  int w = tid >> 6, l = tid & 63;
  int m0 = blockIdx.x * 128;
  int wm = w >> 2;
  int wf = w & 3;
  int lr = l & 15, lk = l >> 4;

  #pragma unroll
  for (int i = 0; i < 8; i++){
    int idx = i*512 + tid;
    int row = idx >> 5, g = idx & 31;
    int su = (g & 24) | ((g & 7) ^ (row & 7));
    gload_lds16(qb + (size_t)(m0+row)*256 + su*8, &sA[idx*8]);
  }
  #pragma unroll
  for (int i = 0; i < 4; i++){
    int idx = i*512 + tid;
    int row = idx >> 5, g = idx & 31;
    int su = (g & 24) | ((g & 7) ^ (row & 7));
    gload_lds16(W1g + (size_t)row*256 + su*8, &sW1[idx*8]);
  }
  #pragma unroll
  for (int i = 0; i < 4; i++){
    int idx = i*512 + tid;
    int row = idx >> 3, g = idx & 7;
    int su = g ^ (row & 7);
    gload_lds16(W2g + (size_t)row*1024 + su*8, &sW2[idx*8]);
  }
  __syncthreads();

  f32x4 acc[4][4] = {};
  for (int cc = 0; cc < 16; ++cc){
    // ---- phase A: h[128,64] = A @ W1chunk^T ----
    f32x4 hacc[4] = {};
    #pragma unroll
    for (int ks = 0; ks < 8; ks++){
      int g = ks*4 + lk;
      int rf = wf*16 + lr;
      v8bf bf1 = *(const v8bf*)&sW1[rf*256 + (((g & 24) | ((g & 7) ^ (rf & 7)))<<3)];
      #pragma unroll
      for (int f = 0; f < 4; f++){
        int ra = wm*64 + f*16 + lr;
        v8bf af = *(const v8bf*)&sA[ra*256 + (((g & 24) | ((g & 7) ^ (ra & 7)))<<3)];
        hacc[f] = __builtin_amdgcn_mfma_f32_16x16x32_bf16(af, bf1, hacc[f], 0, 0, 0);
      }
    }
    {
      int fc = wf*16 + lr;
      float b1v = b1g[cc*64 + fc];
      #pragma unroll
      for (int fi = 0; fi < 4; fi++){
        int mr0 = wm*64 + fi*16 + lk*4;
        #pragma unroll
        for (int r = 0; r < 4; r++){
          float v = fmaxf(hacc[fi][r] + b1v, 0.f);
          int mr = mr0 + r;
          int key = (mr ^ (mr >> 3)) & 7;
          sH[mr*64 + (((fc >> 3) ^ key)<<3) + (fc & 7)] = f2b(v);
        }
      }
    }
    __syncthreads();   // sync_a
    if (cc + 1 < 16){
      int f0n = (cc+1)*64;
      #pragma unroll
      for (int i = 0; i < 4; i++){
        int idx = i*512 + tid;
        int row = idx >> 5, g = idx & 31;
        int su = (g & 24) | ((g & 7) ^ (row & 7));
        gload_lds16(W1g + (size_t)(f0n+row)*256 + su*8, &sW1[idx*8]);
      }
    }
    // ---- phase B: out += h @ W2chunk^T ----
    #pragma unroll
    for (int ks2 = 0; ks2 < 2; ks2++){
      int g = ks2*4 + lk;
      v8bf ha[4], wb[4];
      #pragma unroll
      for (int f = 0; f < 4; f++){
        int rh = wm*64 + f*16 + lr;
        int key = (rh ^ (rh >> 3)) & 7;
        ha[f] = *(const v8bf*)&sH[rh*64 + ((g ^ key)<<3)];
      }
      #pragma unroll
      for (int f = 0; f < 4; f++){
        int rc = wf*64 + f*16 + lr;
        wb[f] = *(const v8bf*)&sW2[rc*64 + ((g ^ (rc & 7))<<3)];
      }
      #pragma unroll
      for (int fi = 0; fi < 4; fi++)
        #pragma unroll
        for (int fc = 0; fc < 4; fc++)
          acc[fi][fc] = __builtin_amdgcn_mfma_f32_16x16x32_bf16(ha[fi], wb[fc], acc[fi][fc], 0, 0, 0);
    }
    __syncthreads();   // sync_b
    if (cc + 1 < 16){
      int f0n = (cc+1)*64;
      #pragma unroll
      for (int i = 0; i < 4; i++){
        int idx = i*512 + tid;
        int row = idx >> 3, g = idx & 7;
        int su = g ^ (row & 7);
        gload_lds16(W2g + (size_t)row*1024 + f0n + su*8, &sW2[idx*8]);
      }
    }
  }

  // ---- fused LN2 epilogue ----
  // y = resid(sA) + delta(acc + b2); LN over 256 cols; write qout.
  float b2v[4], gv[4], bev[4];
  #pragma unroll
  for (int fc = 0; fc < 4; fc++){
    int col = wf*64 + fc*16 + lr;
    b2v[fc] = b2g[col];
    gv[fc]  = n2g[col];
    bev[fc] = n2b[col];
  }
  #pragma unroll
  for (int fi = 0; fi < 4; fi++){
    #pragma unroll
    for (int r = 0; r < 4; r++){
      int row = wm*64 + fi*16 + lk*4 + r;
      #pragma unroll
      for (int fc = 0; fc < 4; fc++){
        int col = wf*64 + fc*16 + lr;
        int cu2 = col >> 3;
        int su = (cu2 & 24) | ((cu2 & 7) ^ (row & 7));
        float resid = b2f(sA[row*256 + su*8 + (col & 7)]);
        acc[fi][fc][r] += b2v[fc] + resid;
      }
    }
  }
  float* psum = (float*)(smem + 32768);   // [128][4] (sW1 area, dead)
  float* psq  = psum + 512;               // [128][4]
  float* mstd = psq + 512;                // [128][2] (beyond st range)
  #pragma unroll
  for (int fi = 0; fi < 4; fi++){
    #pragma unroll
    for (int r = 0; r < 4; r++){
      float s = acc[fi][0][r] + acc[fi][1][r] + acc[fi][2][r] + acc[fi][3][r];
      float q = acc[fi][0][r]*acc[fi][0][r] + acc[fi][1][r]*acc[fi][1][r]
              + acc[fi][2][r]*acc[fi][2][r] + acc[fi][3][r]*acc[fi][3][r];
      s += __shfl_xor(s, 1); s += __shfl_xor(s, 2);
      s += __shfl_xor(s, 4); s += __shfl_xor(s, 8);
      q += __shfl_xor(q, 1); q += __shfl_xor(q, 2);
      q += __shfl_xor(q, 4); q += __shfl_xor(q, 8);
      if (lr == 0){
        int row = wm*64 + fi*16 + lk*4 + r;
        psum[row*4 + wf] = s;
        psq[row*4 + wf]  = q;
      }
    }
  }
  __syncthreads();
  if (tid < 128){
    float s = psum[tid*4] + psum[tid*4+1] + psum[tid*4+2] + psum[tid*4+3];
    float q = psq[tid*4] + psq[tid*4+1] + psq[tid*4+2] + psq[tid*4+3];
    float mean = s * (1.0f/256.0f);
    float var = q * (1.0f/256.0f) - mean*mean;
    mstd[tid*2]   = mean;
    mstd[tid*2+1] = 1.0f / sqrtf(var + 1e-5f);
  }
  __syncthreads();
  unsigned short* st = smem;   // reuse sA area (resid reads all done pre-sync)
  #pragma unroll
  for (int fi = 0; fi < 4; fi++){
    #pragma unroll
    for (int r = 0; r < 4; r++){
      int rowl = wm*64 + fi*16 + lk*4 + r;
      float mean = mstd[rowl*2], rstd = mstd[rowl*2+1];
      #pragma unroll
      for (int fc = 0; fc < 4; fc++){
        int col = wf*64 + fc*16 + lr;
        st[rowl*264 + col] = f2b((acc[fi][fc][r] - mean)*rstd*gv[fc] + bev[fc]);
      }
    }
  }
  __syncthreads();
  #pragma unroll
  for (int it = 0; it < 8; it++){
    int idx = it*512 + tid;
    int row = idx >> 5, c8 = (idx & 31)*8;
    *(uint4*)(qout + (size_t)(m0+row)*256 + c8) = *(const uint4*)&st[row*264 + c8];
  }
}

// ---------------- swh ----------------
__global__ __launch_bounds__(256) void k_swh(const float* __restrict__ g_all,
                                             const float* __restrict__ heat,
                                             const float* __restrict__ soft_b,
                                             unsigned short* __restrict__ swh){
  __shared__ float gl[64*129];
  __shared__ float hml[64];
  int tid = threadIdx.x;
  int blk = blockIdx.x;
  size_t m0 = (size_t)blk*64;
  int b = (int)(m0 >> 12), n0 = (int)(m0 & 4095);
  #pragma unroll
  for (int i = 0; i < 32; i++){
    int idx = i*256 + tid;
    int row = idx >> 7, col = idx & 127;
    gl[row*129 + col] = g_all[(m0 + row)*128 + col];
  }
  if (tid < 64) hml[tid] = heat[(size_t)b*4096 + n0 + tid];
  __syncthreads();
  int k = tid >> 2, j0 = (tid & 3)*16;
  #pragma unroll
  for (int s = 0; s < 2; s++){
    float sb = soft_b[s*64 + k];
    unsigned short vals[16];
    #pragma unroll
    for (int j = 0; j < 16; j++){
      int n = j0 + j;
      float h = hml[n];
      float hm = s ? (1.0f - h) : h;
      vals[j] = f2b((gl[n*129 + s*64 + k]*hm + sb)*hm);
    }
    unsigned short* dst = swh + (((size_t)b*2 + s)*64 + k)*4096 + n0 + j0;
    uint4 o0, o1;
    o0.x = vals[0] | ((uint32_t)vals[1]<<16);  o0.y = vals[2] | ((uint32_t)vals[3]<<16);
    o0.z = vals[4] | ((uint32_t)vals[5]<<16);  o0.w = vals[6] | ((uint32_t)vals[7]<<16);
    o1.x = vals[8] | ((uint32_t)vals[9]<<16);  o1.y = vals[10]| ((uint32_t)vals[11]<<16);
    o1.z = vals[12]| ((uint32_t)vals[13]<<16); o1.w = vals[14]| ((uint32_t)vals[15]<<16);
    *(uint4*)dst = o0;
    *(uint4*)(dst + 8) = o1;
  }
}

// ---------------- pool GEMM (split-K) ----------------
__global__ __launch_bounds__(256) void k_poolgemm(
    const unsigned short* __restrict__ swh, const unsigned short* __restrict__ featC,
    float* __restrict__ pp){
  __shared__ unsigned short ldsA[128*64];
  __shared__ unsigned short ldsB[128*64];
  int tid = threadIdx.x;
  int w = tid >> 6, l = tid & 63;
  int kc = blockIdx.x, nt = blockIdx.y, b = blockIdx.z;
  int wr = w >> 1, wc = w & 1;
  int lr = l & 15, lk = l >> 4;
  const unsigned short* A = swh  + (size_t)b*128*4096 + kc*512;
  const unsigned short* W = featC + ((size_t)b*256 + nt*128)*4096 + kc*512;
  f32x4 acc[4][4] = {};
  for (int k0 = 0; k0 < 512; k0 += 64){
    #pragma unroll
    for (int i = 0; i < 4; i++){
      int idx = i*256 + tid;
      int row = idx >> 3, su = (idx & 7) ^ (row & 7);
      gload_lds16(A + (size_t)row*4096 + k0 + su*8, &ldsA[idx*8]);
    }
    #pragma unroll
    for (int i = 0; i < 4; i++){
      int idx = i*256 + tid;
      int row = idx >> 3, su = (idx & 7) ^ (row & 7);
      gload_lds16(W + (size_t)row*4096 + k0 + su*8, &ldsB[idx*8]);
    }
    __syncthreads();
    #pragma unroll
    for (int kk = 0; kk < 2; kk++){
      v8bf af[4], bfr[4];
      #pragma unroll
      for (int f = 0; f < 4; f++){
        int ra = wr*64 + f*16 + lr;
        int rb2 = wc*64 + f*16 + lr;
        int u = kk*4 + lk;
        af[f]  = *(const v8bf*)(&ldsA[ra*64 + ((u ^ (ra&7))<<3)]);
        bfr[f] = *(const v8bf*)(&ldsB[rb2*64 + ((u ^ (rb2&7))<<3)]);
      }
      #pragma unroll
      for (int fi = 0; fi < 4; fi++)
        #pragma unroll
        for (int fj = 0; fj < 4; fj++)
          acc[fi][fj] = __builtin_amdgcn_mfma_f32_16x16x32_bf16(af[fi], bfr[fj], acc[fi][fj], 0, 0, 0);
    }
    __syncthreads();
  }
  float* dst = pp + ((size_t)kc*8 + b)*128*256;
  #pragma unroll
  for (int fj = 0; fj < 4; fj++){
    int col = nt*128 + wc*64 + fj*16 + lr;
    #pragma unroll
    for (int fi = 0; fi < 4; fi++){
      int rb = wr*64 + fi*16 + lk*4;
      #pragma unroll
      for (int r = 0; r < 4; r++)
        dst[(size_t)(rb + r)*256 + col] = acc[fi][fj][r];
    }
  }
}

// ---------------- reduce split-K partials ----------------
__global__ __launch_bounds__(256) void k_pool2b(const float* __restrict__ pp,
                                                unsigned short* __restrict__ pool_bf_s){
  int bk = blockIdx.x, side = blockIdx.y, c = threadIdx.x;
  int b = bk >> 6, k = bk & 63;
  float s = 0.f;
  #pragma unroll
  for (int kc = 0; kc < 8; kc++)
    s += pp[(((size_t)kc*8 + b)*128 + side*64 + k)*256 + c];
  pool_bf_s[((size_t)side*512 + bk)*256 + c] = f2b(s);
}

// ---------------- MFMA attention ----------------
__global__ __launch_bounds__(256) void k_attn2(
    const unsigned short* __restrict__ qq, const unsigned short* __restrict__ kk,
    const unsigned short* __restrict__ vvT, unsigned short* __restrict__ obf){
  __shared__ unsigned short sk[64*256];
  __shared__ unsigned short svT[256*64];
  __shared__ unsigned short sp[4][16*64];
  __shared__ unsigned short sow[4][16*32];
  int tid = threadIdx.x, w = tid >> 6, l = tid & 63;
  int blk = blockIdx.x, b = blk >> 6;
  int l15 = l & 15, lg = l >> 4;
  const uint4* ksrc = (const uint4*)(kk + (size_t)b*64*256);
  #pragma unroll
  for (int i = 0; i < 8; i++){
    int u = i*256 + tid;
    int row = u >> 5, j = u & 31;
    *(uint4*)&sk[row*256 + ((j ^ (row&7))<<3)] = ksrc[u];
  }
  const uint4* vsrc = (const uint4*)(vvT + (size_t)b*256*64);
  #pragma unroll
  for (int i = 0; i < 8; i++){
    int u = i*256 + tid;
    int row = u >> 3, j = u & 7;
    *(uint4*)&svT[row*64 + ((j ^ (row&7))<<3)] = vsrc[u];
  }
  __syncthreads();
  size_t qrow = (size_t)blk*64 + w*16 + l15;
  for (int h = 0; h < 8; h++){
    v8bf aq = *(const v8bf*)(qq + qrow*256 + h*32 + lg*8);
    f32x4 s[4];
    #pragma unroll
    for (int kt = 0; kt < 4; kt++){
      int row = kt*16 + l15;
      v8bf bk = *(const v8bf*)&sk[row*256 + (((h*4 + lg) ^ (row&7))<<3)];
      f32x4 z = {};
      s[kt] = __builtin_amdgcn_mfma_f32_16x16x32_bf16(aq, bk, z, 0, 0, 0);
    }
    #pragma unroll
    for (int r = 0; r < 4; r++){
      float v0 = s[0][r]*SCALE_, v1 = s[1][r]*SCALE_;
      float v2 = s[2][r]*SCALE_, v3 = s[3][r]*SCALE_;
      float mx = fmaxf(fmaxf(v0, v1), fmaxf(v2, v3));
      mx = fmaxf(mx, __shfl_xor(mx, 1));
      mx = fmaxf(mx, __shfl_xor(mx, 2));
      mx = fmaxf(mx, __shfl_xor(mx, 4));
      mx = fmaxf(mx, __shfl_xor(mx, 8));
      float e0 = __expf(v0-mx), e1 = __expf(v1-mx);
      float e2 = __expf(v2-mx), e3 = __expf(v3-mx);
      float sum = e0+e1+e2+e3;
      sum += __shfl_xor(sum, 1); sum += __shfl_xor(sum, 2);
      sum += __shfl_xor(sum, 4); sum += __shfl_xor(sum, 8);
      float inv = 1.0f/sum;
      s[0][r] = e0*inv; s[1][r] = e1*inv; s[2][r] = e2*inv; s[3][r] = e3*inv;
    }
    #pragma unroll
    for (int kt = 0; kt < 4; kt++){
      int colu = kt*2 + (l15>>3);
      #pragma unroll
      for (int r = 0; r < 4; r++){
        int row = lg*4 + r;
        sp[w][row*64 + ((colu ^ (row&7))<<3) + (l&7)] = f2b(s[kt][r]);
      }
    }
    f32x4 o[2] = {};
    #pragma unroll
    for (int k2 = 0; k2 < 2; k2++){
      v8bf pa = *(const v8bf*)&sp[w][l15*64 + (((k2*4 + lg) ^ (l15&7))<<3)];
      #pragma unroll
      for (int dt = 0; dt < 2; dt++){
        int vrow = h*32 + dt*16 + l15;
        v8bf bv = *(const v8bf*)&svT[vrow*64 + (((k2*4 + lg) ^ (vrow&7))<<3)];
        o[dt] = __builtin_amdgcn_mfma_f32_16x16x32_bf16(pa, bv, o[dt], 0, 0, 0);
      }
    }
    #pragma unroll
    for (int dt = 0; dt < 2; dt++)
      #pragma unroll
      for (int r = 0; r < 4; r++)
        sow[w][(lg*4 + r)*32 + dt*16 + l15] = f2b(o[dt][r]);
    uint4 ov = *(const uint4*)&sow[w][l15*32 + lg*8];
    *(uint4*)(obf + qrow*256 + h*32 + lg*8) = ov;
  }
}

// ---------------- residual + LayerNorm (n1 path) ----------------
template<int RF32>
__global__ __launch_bounds__(256) void k_ln2(
    const void* __restrict__ resid, const unsigned short* __restrict__ delta,
    const float* __restrict__ g, const float* __restrict__ bta,
    unsigned short* __restrict__ qout){
  int wv = threadIdx.x >> 6, l = threadIdx.x & 63;
  size_t m = (size_t)blockIdx.x*4 + wv;
  uint2 dv = *(const uint2*)(delta + m*256 + l*4);
  float d0 = b2f((unsigned short)(dv.x & 0xffff)), d1 = b2f((unsigned short)(dv.x >> 16));
  float d2 = b2f((unsigned short)(dv.y & 0xffff)), d3 = b2f((unsigned short)(dv.y >> 16));
  float x0, x1, x2, x3;
  if (RF32){
    float4 rv = *(const float4*)((const float*)resid + m*256 + l*4);
    x0 = rv.x+d0; x1 = rv.y+d1; x2 = rv.z+d2; x3 = rv.w+d3;
  } else {
    uint2 rv = *(const uint2*)((const unsigned short*)resid + m*256 + l*4);
    x0 = b2f((unsigned short)(rv.x & 0xffff)) + d0;
    x1 = b2f((unsigned short)(rv.x >> 16)) + d1;
    x2 = b2f((unsigned short)(rv.y & 0xffff)) + d2;
    x3 = b2f((unsigned short)(rv.y >> 16)) + d3;
  }
  float s = x0+x1+x2+x3;
  float ss = x0*x0+x1*x1+x2*x2+x3*x3;
  #pragma unroll
  for (int off = 32; off; off >>= 1){
    s  += __shfl_xor(s, off);
    ss += __shfl_xor(ss, off);
  }
  float mean = s * (1.0f/256.0f);
  float var = ss * (1.0f/256.0f) - mean*mean;
  float rstd = 1.0f / sqrtf(var + 1e-5f);
  float4 gv = *(const float4*)(g + l*4);
  float4 bv = *(const float4*)(bta + l*4);
  float y0 = (x0-mean)*rstd*gv.x + bv.x;
  float y1 = (x1-mean)*rstd*gv.y + bv.y;
  float y2 = (x2-mean)*rstd*gv.z + bv.z;
  float y3 = (x3-mean)*rstd*gv.w + bv.w;
  uint32_t p0 = (uint32_t)f2b(y0) | ((uint32_t)f2b(y1)<<16);
  uint32_t p1 = (uint32_t)f2b(y2) | ((uint32_t)f2b(y3)<<16);
  *(uint2*)(qout + m*256 + l*4) = make_uint2(p0,p1);
}

// ---------------- final select + transpose ----------------
__global__ __launch_bounds__(256) void k_select(
    const unsigned short* __restrict__ qA, const unsigned short* __restrict__ qB,
    const float* __restrict__ featT, const float* __restrict__ heat,
    const int* __restrict__ counts, float* __restrict__ out){
  __shared__ float t[32][33];
  int b = blockIdx.z;
  int n0 = blockIdx.x*32, c0 = blockIdx.y*32;
  int tx = threadIdx.x, ty = threadIdx.y;
  bool valid = (counts[b*2] > 0) && (counts[b*2+1] > 0);
  #pragma unroll
  for (int i = 0; i < 4; i++){
    int nl = ty*4+i;
    size_t m = (size_t)b*4096 + n0 + nl;
    float v;
    if (!valid) v = featT[m*256 + c0 + tx];
    else {
      bool fg = heat[(size_t)b*4096 + n0 + nl] >= 0.5f;
      v = fg ? b2f(qA[m*256 + c0 + tx]) : b2f(qB[m*256 + c0 + tx]);
    }
    t[nl][tx] = v;
  }
  __syncthreads();
  #pragma unroll
  for (int i = 0; i < 4; i++){
    int cl = ty*4+i;
    out[((size_t)b*256 + c0 + cl)*4096 + n0 + tx] = t[tx][cl];
  }
}

extern "C" void kernel_launch(void* const* d_in, const int* in_sizes, int n_in,
                              void* d_out, int out_size, void* d_ws, size_t ws_size,
                              hipStream_t stream){
  const float* x         = (const float*)d_in[0];
  const float* y         = (const float*)d_in[1];
  const float* proj_w    = (const float*)d_in[2];
  const float* proj_b    = (const float*)d_in[3];
  const float* sal_w     = (const float*)d_in[4];
  const float* sal_b     = (const float*)d_in[5];
  const float* soft_w    = (const float*)d_in[6];
  const float* soft_b    = (const float*)d_in[7];
  const float* attn_in_w = (const float*)d_in[8];
  const float* attn_in_b = (const float*)d_in[9];
  const float* attn_out_w= (const float*)d_in[10];
  const float* attn_out_b= (const float*)d_in[11];
  const float* n1_g      = (const float*)d_in[12];
  const float* n1_b      = (const float*)d_in[13];
  const float* ffn_w1    = (const float*)d_in[14];
  const float* ffn_b1    = (const float*)d_in[15];
  const float* ffn_w2    = (const float*)d_in[16];
  const float* ffn_b2    = (const float*)d_in[17];
  const float* n2_g      = (const float*)d_in[18];
  const float* n2_b      = (const float*)d_in[19];
  float* out = (float*)d_out;

  char* p = (char*)d_ws;
  auto alloc = [&](size_t bytes){ char* r = p; p += (bytes + 255) & ~(size_t)255; return r; };
  unsigned short* hbf   = (unsigned short*)alloc((size_t)M_*FF_*2);
  unsigned short* xcT   = hbf;
  unsigned short* qq_bf = hbf;
  float* featT = (float*)alloc((size_t)M_*C_*4);
  unsigned short* qAb = (unsigned short*)alloc((size_t)M_*C_*2);
  unsigned short* swh = qAb;
  unsigned short* qBb = (unsigned short*)alloc((size_t)M_*C_*2);
  unsigned short* obf = (unsigned short*)alloc((size_t)M_*C_*2);
  unsigned short* featC = obf;
  unsigned short* featbf = (unsigned short*)alloc((size_t)M_*C_*2);
  unsigned short* tmpb = (unsigned short*)alloc((size_t)M_*C_*2);
  float* g_all = (float*)tmpb;
  float* pp    = (float*)alloc((size_t)8*8*128*256*4);
  double* salp = (double*)pp;
  unsigned short* pool_bf_s = (unsigned short*)alloc((size_t)2*512*256*2);
  unsigned short* kk_bf = (unsigned short*)alloc((size_t)B_*K_*C_*2);
  unsigned short* vvT_bf= (unsigned short*)alloc((size_t)B_*C_*K_*2);
  float* heat = (float*)alloc((size_t)B_*N_*4);
  double* u   = (double*)alloc(513*8);
  int* counts = (int*)alloc(64);
  float* zbias = (float*)alloc(512);
  unsigned short* projw_bf = (unsigned short*)alloc((size_t)C_*512*2);
  unsigned short* aiw_bf = (unsigned short*)alloc((size_t)2*L_*768*C_*2);
  unsigned short* aow_bf = (unsigned short*)alloc((size_t)2*L_*C_*C_*2);
  unsigned short* f1w_bf = (unsigned short*)alloc((size_t)2*L_*FF_*C_*2);
  unsigned short* f2w_bf = (unsigned short*)alloc((size_t)2*L_*C_*FF_*2);
  unsigned short* sw2_bf = (unsigned short*)alloc((size_t)2*K_*C_*2);

  hipMemsetAsync(counts, 0, 64, stream);
  hipMemsetAsync(zbias, 0, 512, stream);
  k_compute_u<<<1, 512, 0, stream>>>(sal_w, proj_w, proj_b, sal_b, u);
  k_sal_part<<<dim3(128, 16), 256, 0, stream>>>(x, y, u, salp);
  k_sal_red<<<128, 256, 0, stream>>>(salp, u, heat, counts);

  auto conv = [&](const float* s, unsigned short* d, size_t n){
    k_f32_to_bf16<<<(unsigned)((n/4 + 255)/256), 256, 0, stream>>>(s, d, (int)n);
  };
  conv(proj_w,     projw_bf, (size_t)C_*512);
  conv(attn_in_w,  aiw_bf,   (size_t)2*L_*768*C_);
  conv(attn_out_w, aow_bf,   (size_t)2*L_*C_*C_);
  conv(ffn_w1,     f1w_bf,   (size_t)2*L_*FF_*C_);
  conv(ffn_w2,     f2w_bf,   (size_t)2*L_*C_*FF_);
  conv(soft_w,     sw2_bf,   (size_t)2*K_*C_);

  k_build_xcT<<<dim3(N_/32, 512/32, B_), dim3(32,8), 0, stream>>>(x, y, xcT);
  k_gemm_bt<0><<<dim3(M_/128, C_/128), 256, 0, stream>>>(xcT, projw_bf, proj_b, featT, M_, C_, 512);
  k_featmir<<<dim3(N_/32, C_/32, B_), dim3(32,8), 0, stream>>>(featT, featbf, featC);

  k_gemm_bt<0><<<dim3(M_/128, 1), 256, 0, stream>>>(featbf, sw2_bf, zbias, g_all, M_, 128, C_);
  k_swh<<<M_/64, 256, 0, stream>>>(g_all, heat, soft_b, swh);
  k_poolgemm<<<dim3(8, 2, B_), 256, 0, stream>>>(swh, featC, pp);
  k_pool2b<<<dim3(512, 2), 256, 0, stream>>>(pp, pool_bf_s);

  for (int side = 0; side < 2; ++side){
    unsigned short* qb = side ? qBb : qAb;
    const unsigned short* poolS = pool_bf_s + (size_t)side*512*256;
    for (int lyr = 0; lyr < L_; ++lyr){
      int sl = side*L_ + lyr;
      const unsigned short* iw = aiw_bf + (size_t)sl*768*C_;
      const float* ib = attn_in_b + (size_t)sl*768;
      const unsigned short* qin = (lyr == 0) ? featbf : qb;
      k_gemm_bt<2><<<dim3(M_/128, C_/128), 256, 0, stream>>>(qin, iw, ib, qq_bf, M_, C_, C_);
      k_kv<<<dim3(4, 2, 2), 256, 0, stream>>>(poolS, iw, ib, kk_bf, vvT_bf);
      k_attn2<<<M_/64, 256, 0, stream>>>(qq_bf, kk_bf, vvT_bf, obf);
      k_gemm_bt<2><<<dim3(M_/128, C_/128), 256, 0, stream>>>(obf, aow_bf + (size_t)sl*C_*C_, attn_out_b + (size_t)sl*C_, tmpb, M_, C_, C_);
      if (lyr == 0)
        k_ln2<1><<<M_/4, 256, 0, stream>>>(featT, tmpb, n1_g + (size_t)sl*C_, n1_b + (size_t)sl*C_, qb);
      else
        k_ln2<0><<<M_/4, 256, 0, stream>>>(qb, tmpb, n1_g + (size_t)sl*C_, n1_b + (size_t)sl*C_, qb);
      k_ffn<<<M_/128, 512, 0, stream>>>(qb, f1w_bf + (size_t)sl*FF_*C_, ffn_b1 + (size_t)sl*FF_,
                                        f2w_bf + (size_t)sl*C_*FF_, ffn_b2 + (size_t)sl*C_,
                                        n2_g + (size_t)sl*C_, n2_b + (size_t)sl*C_, qb);
    }
  }
  k_select<<<dim3(N_/32, C_/32, B_), dim3(32,8), 0, stream>>>(qAb, qBb, featT, heat, counts, out);
}